// Round 1
// baseline (1612.510 us; speedup 1.0000x reference)
//
#include <hip/hip_runtime.h>

// Problem constants
#define BDIM   8
#define NPIX   250000   // 500*500
#define G1N    62500    // 250*250
#define G2N    15625    // 125*125
#define CAP0   4096     // cap on level-0 active sites per image (~1250 expected)
#define CAP1   4096     // level-1 cap (~1240 expected)
#define CAPM   2048     // level-2 cap = reference M
#define CH     64
#define ACH    128
#define NHEADS 4
#define DH     32

static constexpr float BN_INV    = 0.99999500003749969f;   // 1/sqrt(1+1e-5)
static constexpr float ATT_SCALE = 0.17677669529663687f;   // 1/sqrt(32)

// Workspace element offsets (4-byte units)
static constexpr size_t E_MAP0  = 0;                                   // int [B*NPIX]
static constexpr size_t E_MAP1  = E_MAP0 + (size_t)BDIM*NPIX;          // int [B*G1N]
static constexpr size_t E_CNT   = E_MAP1 + (size_t)BDIM*G1N;           // int [24] (L0,L1,L2 x B)
static constexpr size_t E_LIST0 = E_CNT + 32;                          // int [B*CAP0]
static constexpr size_t E_LIST1 = E_LIST0 + (size_t)BDIM*CAP0;         // int [B*CAP1]
static constexpr size_t E_LIST2 = E_LIST1 + (size_t)BDIM*CAP1;         // int [B*CAPM]
static constexpr size_t E_Y0    = E_LIST2 + (size_t)BDIM*CAPM;         // f32 [B*CAP0*32]
static constexpr size_t E_Y1    = E_Y0 + (size_t)BDIM*CAP0*32;         // f32 [B*CAP1*64]
static constexpr size_t E_FE    = E_Y1 + (size_t)BDIM*CAP1*64;         // f32 [B*CAPM*64]
static constexpr size_t E_Q     = E_FE + (size_t)BDIM*CAPM*64;         // f32 [B*4*CAPM*32]
static constexpr size_t E_K     = E_Q + (size_t)BDIM*NHEADS*CAPM*DH;
static constexpr size_t E_V     = E_K + (size_t)BDIM*NHEADS*CAPM*DH;
static constexpr size_t E_O     = E_V + (size_t)BDIM*NHEADS*CAPM*DH;   // f32 [B*CAPM*128]
// end ~ 58 MB

__global__ void k_active0(const float* __restrict__ x, int* __restrict__ map0,
                          int* __restrict__ list0, int* __restrict__ cnt) {
  int idx = blockIdx.x * 256 + threadIdx.x;
  if (idx >= BDIM * NPIX) return;
  float v = x[idx];
  if (v != 0.f) {
    int b = idx / NPIX;
    int pix = idx - b * NPIX;
    int slot = atomicAdd(&cnt[b], 1);
    if (slot < CAP0) { list0[b * CAP0 + slot] = pix; map0[idx] = slot + 1; }
  }
}

__global__ void k_y0(const float* __restrict__ x, const float* __restrict__ w0,
                     const float* __restrict__ b0, const float* __restrict__ g0,
                     const float* __restrict__ be0,
                     const int* __restrict__ list0, const int* __restrict__ cnt,
                     float* __restrict__ y0) {
  int t = blockIdx.x * 256 + threadIdx.x;   // B*CAP0*32 threads
  int b = t >> 17;                          // CAP0*32 = 131072
  int r = t & 131071;
  int slot = r >> 5, c = r & 31;
  int n = min(cnt[b], CAP0);
  if (slot >= n) return;
  int pix = list0[b * CAP0 + slot];
  int i = pix / 500, j = pix - i * 500;
  float acc = b0[c];
#pragma unroll
  for (int di = 0; di < 3; ++di) {
    int ii = i + di - 1;
    if ((unsigned)ii >= 500u) continue;
#pragma unroll
    for (int dj = 0; dj < 3; ++dj) {
      int jj = j + dj - 1;
      if ((unsigned)jj >= 500u) continue;
      acc += x[b * NPIX + ii * 500 + jj] * w0[(di * 3 + dj) * 32 + c];
    }
  }
  float o = g0[c] * acc * BN_INV + be0[c];
  y0[((size_t)(b * CAP0) + slot) * 32 + c] = fmaxf(o, 0.f);
}

__global__ void k_active1(const int* __restrict__ map0, int* __restrict__ map1,
                          int* __restrict__ list1, int* __restrict__ cnt) {
  int idx = blockIdx.x * 256 + threadIdx.x;
  if (idx >= BDIM * G1N) return;
  int b = idx / G1N;
  int p = idx - b * G1N;
  int i = p / 250, j = p - i * 250;
  const int* m = map0 + b * NPIX + (2 * i) * 500 + 2 * j;
  if (m[0] | m[1] | m[500] | m[501]) {
    int slot = atomicAdd(&cnt[BDIM + b], 1);
    if (slot < CAP1) { list1[b * CAP1 + slot] = p; map1[idx] = slot + 1; }
  }
}

__global__ void k_y1(const float* __restrict__ y0, const float* __restrict__ w1,
                     const float* __restrict__ b1, const float* __restrict__ g1,
                     const float* __restrict__ be1,
                     const int* __restrict__ map0, const int* __restrict__ list1,
                     const int* __restrict__ cnt, float* __restrict__ y1) {
  int b = blockIdx.x >> 12;         // CAP1 = 4096
  int slot = blockIdx.x & 4095;
  int n = min(cnt[BDIM + b], CAP1);
  if (slot >= n) return;
  int p = list1[b * CAP1 + slot];
  int i = p / 250, j = p - i * 250;
  __shared__ float in[4][32];
  for (int idx = threadIdx.x; idx < 128; idx += 64) {
    int pp = idx >> 5, ci = idx & 31;
    int di = pp >> 1, dj = pp & 1;
    int s0 = map0[b * NPIX + (2 * i + di) * 500 + (2 * j + dj)];
    in[pp][ci] = s0 ? y0[((size_t)(b * CAP0) + (s0 - 1)) * 32 + ci] : 0.f;
  }
  __syncthreads();
  int co = threadIdx.x;
  float acc = b1[co];
#pragma unroll
  for (int pp = 0; pp < 4; ++pp)
#pragma unroll
    for (int ci = 0; ci < 32; ++ci)
      acc += in[pp][ci] * w1[((pp << 5) + ci) * 64 + co];
  float o = g1[co] * acc * BN_INV + be1[co];
  y1[((size_t)(b * CAP1) + slot) * 64 + co] = fmaxf(o, 0.f);
}

__global__ void k_active2(const int* __restrict__ map1, int* __restrict__ list2,
                          int* __restrict__ cnt) {
  int idx = blockIdx.x * 256 + threadIdx.x;
  if (idx >= BDIM * G2N) return;
  int b = idx / G2N;
  int p = idx - b * G2N;
  int i = p / 125, j = p - i * 125;
  const int* m = map1 + b * G1N + (2 * i) * 250 + 2 * j;
  if (m[0] | m[1] | m[250] | m[251]) {
    int slot = atomicAdd(&cnt[2 * BDIM + b], 1);
    if (slot < CAPM) list2[b * CAPM + slot] = p;
  }
}

__global__ void k_y2(const float* __restrict__ y1, const float* __restrict__ w2,
                     const float* __restrict__ b2, const float* __restrict__ g2,
                     const float* __restrict__ be2,
                     const int* __restrict__ map1, const int* __restrict__ list2,
                     const int* __restrict__ cnt, float* __restrict__ feats) {
  int b = blockIdx.x >> 11;         // CAPM = 2048
  int slot = blockIdx.x & 2047;
  int n = min(cnt[2 * BDIM + b], CAPM);
  if (slot >= n) return;
  int p = list2[b * CAPM + slot];
  int i = p / 125, j = p - i * 125;
  __shared__ float in[4][64];
  for (int idx = threadIdx.x; idx < 256; idx += 64) {
    int pp = idx >> 6, ci = idx & 63;
    int s1 = map1[b * G1N + (2 * i + (pp >> 1)) * 250 + (2 * j + (pp & 1))];
    in[pp][ci] = s1 ? y1[((size_t)(b * CAP1) + (s1 - 1)) * 64 + ci] : 0.f;
  }
  __syncthreads();
  int co = threadIdx.x;
  float acc = b2[co];
#pragma unroll
  for (int pp = 0; pp < 4; ++pp)
#pragma unroll
    for (int ci = 0; ci < 64; ++ci)
      acc += in[pp][ci] * w2[((pp << 6) + ci) * 64 + co];
  float o = g2[co] * acc * BN_INV + be2[co];
  feats[((size_t)(b * CAPM) + slot) * 64 + co] = fmaxf(o, 0.f);
}

__global__ void k_qkv(const float* __restrict__ feats, const int* __restrict__ list2,
                      const int* __restrict__ cnt,
                      const float* __restrict__ wpe, const float* __restrict__ bpe,
                      const float* __restrict__ wq, const float* __restrict__ bq,
                      const float* __restrict__ wk, const float* __restrict__ bk,
                      const float* __restrict__ wv, const float* __restrict__ bv,
                      int layer, float* __restrict__ qbuf, float* __restrict__ kbuf,
                      float* __restrict__ vbuf) {
  int b = blockIdx.x >> 11;
  int slot = blockIdx.x & 2047;
  int n = min(cnt[2 * BDIM + b], CAPM);
  if (slot >= n) return;
  __shared__ float h[64];
  if (threadIdx.x < 64) {
    int p = list2[b * CAPM + slot];
    int i = p / 125, j = p - i * 125;
    float p0 = (float)i * (1.f / 125.f), p1 = (float)j * (1.f / 125.f);
    h[threadIdx.x] = feats[((size_t)(b * CAPM) + slot) * 64 + threadIdx.x]
                   + p0 * wpe[(layer * 2 + 0) * 64 + threadIdx.x]
                   + p1 * wpe[(layer * 2 + 1) * 64 + threadIdx.x]
                   + bpe[layer * 64 + threadIdx.x];
  }
  __syncthreads();
  int o = threadIdx.x;                 // 0..127
  float aq = bq[layer * 128 + o];
  float ak = bk[layer * 128 + o];
  float av = bv[layer * 128 + o];
  const float* wq_ = wq + (size_t)layer * 64 * 128 + o;
  const float* wk_ = wk + (size_t)layer * 64 * 128 + o;
  const float* wv_ = wv + (size_t)layer * 64 * 128 + o;
#pragma unroll 8
  for (int c = 0; c < 64; ++c) {
    float hv = h[c];
    aq += hv * wq_[c * 128];
    ak += hv * wk_[c * 128];
    av += hv * wv_[c * 128];
  }
  int hd = o >> 5, d = o & 31;
  size_t base = (((size_t)(b * NHEADS + hd)) * CAPM + slot) * DH + d;
  qbuf[base] = aq; kbuf[base] = ak; vbuf[base] = av;
}

__global__ __launch_bounds__(256) void k_attn(const float* __restrict__ qbuf,
                                              const float* __restrict__ kbuf,
                                              const float* __restrict__ vbuf,
                                              const int* __restrict__ cnt,
                                              float* __restrict__ obuf) {
  int bid = blockIdx.x;
  int qblk = bid & 7;                // CAPM/256 = 8
  int h = (bid >> 3) & 3;
  int b = bid >> 5;
  int n = min(cnt[2 * BDIM + b], CAPM);
  int q0 = qblk * 256;
  if (q0 >= n) return;               // uniform across block
  int qi = q0 + (int)threadIdx.x;
  bool qv = qi < n;
  size_t bh = (size_t)(b * NHEADS + h) * CAPM;

  float q[32];
  if (qv) {
    const float4* qp = (const float4*)(qbuf + (bh + qi) * DH);
#pragma unroll
    for (int u = 0; u < 8; ++u) {
      float4 t = qp[u];
      q[4 * u] = t.x; q[4 * u + 1] = t.y; q[4 * u + 2] = t.z; q[4 * u + 3] = t.w;
    }
  } else {
#pragma unroll
    for (int u = 0; u < 32; ++u) q[u] = 0.f;
  }
  float m = -1e30f, l = 0.f;
  float acc[32];
#pragma unroll
  for (int u = 0; u < 32; ++u) acc[u] = 0.f;

  __shared__ float Kt[64][32];
  __shared__ float Vt[64][32];

  for (int t0 = 0; t0 < n; t0 += 64) {
    int tl = min(64, n - t0);
    __syncthreads();
    for (int idx = threadIdx.x; idx < 512; idx += 256) {
      int kk = idx >> 3, u = idx & 7;
      float4 kvv = make_float4(0.f, 0.f, 0.f, 0.f);
      float4 vvv = make_float4(0.f, 0.f, 0.f, 0.f);
      if (kk < tl) {
        kvv = *(const float4*)(kbuf + (bh + t0 + kk) * DH + 4 * u);
        vvv = *(const float4*)(vbuf + (bh + t0 + kk) * DH + 4 * u);
      }
      ((float4*)Kt)[idx] = kvv;
      ((float4*)Vt)[idx] = vvv;
    }
    __syncthreads();
    for (int kk = 0; kk < tl; ++kk) {
      float s = 0.f;
#pragma unroll
      for (int u = 0; u < 8; ++u) {
        float4 kr = *(const float4*)&Kt[kk][4 * u];
        s += q[4 * u] * kr.x + q[4 * u + 1] * kr.y + q[4 * u + 2] * kr.z + q[4 * u + 3] * kr.w;
      }
      s *= ATT_SCALE;
      float mn = fmaxf(m, s);
      float f1 = __expf(m - mn), f2 = __expf(s - mn);
      l = l * f1 + f2;
      m = mn;
#pragma unroll
      for (int u = 0; u < 8; ++u) {
        float4 vr = *(const float4*)&Vt[kk][4 * u];
        acc[4 * u]     = acc[4 * u] * f1     + f2 * vr.x;
        acc[4 * u + 1] = acc[4 * u + 1] * f1 + f2 * vr.y;
        acc[4 * u + 2] = acc[4 * u + 2] * f1 + f2 * vr.z;
        acc[4 * u + 3] = acc[4 * u + 3] * f1 + f2 * vr.w;
      }
    }
  }
  if (qv) {
    float inv = 1.f / l;
    float* op = obuf + ((size_t)b * CAPM + qi) * ACH + h * DH;
#pragma unroll
    for (int u = 0; u < 8; ++u) {
      float4 t = make_float4(acc[4 * u] * inv, acc[4 * u + 1] * inv,
                             acc[4 * u + 2] * inv, acc[4 * u + 3] * inv);
      *(float4*)(op + 4 * u) = t;
    }
  }
}

__global__ void k_proj(const float* __restrict__ obuf, const float* __restrict__ wo,
                       const float* __restrict__ bo, const int* __restrict__ cnt,
                       int layer, float* __restrict__ feats) {
  int b = blockIdx.x >> 11;
  int slot = blockIdx.x & 2047;
  int n = min(cnt[2 * BDIM + b], CAPM);
  if (slot >= n) return;
  __shared__ float orow[128];
  orow[threadIdx.x] = obuf[((size_t)b * CAPM + slot) * ACH + threadIdx.x];
  orow[threadIdx.x + 64] = obuf[((size_t)b * CAPM + slot) * ACH + 64 + threadIdx.x];
  __syncthreads();
  int co = threadIdx.x;
  float acc = bo[layer * 64 + co];
  const float* w = wo + (size_t)layer * 128 * 64 + co;
#pragma unroll 8
  for (int c = 0; c < 128; ++c) acc += orow[c] * w[c * 64];
  feats[((size_t)(b * CAPM) + slot) * 64 + co] += acc;
}

__global__ void k_head(const float* __restrict__ feats, const float* __restrict__ wh,
                       const float* __restrict__ bh, const int* __restrict__ cnt,
                       float* __restrict__ out) {
  int b = blockIdx.x;
  int n = min(cnt[2 * BDIM + b], CAPM);
  int c = threadIdx.x;
  float s = 0.f;
  for (int mm = 0; mm < n; ++mm) s += feats[((size_t)(b * CAPM) + mm) * 64 + c];
  __shared__ float pooled[64];
  pooled[c] = s / (float)max(n, 1);
  __syncthreads();
  if (c < 4) {
    float o = bh[c];
#pragma unroll
    for (int c2 = 0; c2 < 64; ++c2) o += pooled[c2] * wh[c2 * 4 + c];
    out[b * 4 + c] = o;
  }
}

extern "C" void kernel_launch(void* const* d_in, const int* in_sizes, int n_in,
                              void* d_out, int out_size, void* d_ws, size_t ws_size,
                              hipStream_t stream) {
  const float* x   = (const float*)d_in[0];
  const float* w0  = (const float*)d_in[1];
  const float* b0  = (const float*)d_in[2];
  const float* g0  = (const float*)d_in[3];
  const float* be0 = (const float*)d_in[4];
  const float* w1  = (const float*)d_in[5];
  const float* b1  = (const float*)d_in[6];
  const float* g1  = (const float*)d_in[7];
  const float* be1 = (const float*)d_in[8];
  const float* w2  = (const float*)d_in[9];
  const float* b2  = (const float*)d_in[10];
  const float* g2  = (const float*)d_in[11];
  const float* be2 = (const float*)d_in[12];
  const float* wpe = (const float*)d_in[13];
  const float* bpe = (const float*)d_in[14];
  const float* wq  = (const float*)d_in[15];
  const float* bq  = (const float*)d_in[16];
  const float* wk  = (const float*)d_in[17];
  const float* bk  = (const float*)d_in[18];
  const float* wv  = (const float*)d_in[19];
  const float* bv  = (const float*)d_in[20];
  const float* wo  = (const float*)d_in[21];
  const float* bo  = (const float*)d_in[22];
  const float* wh  = (const float*)d_in[23];
  const float* bh  = (const float*)d_in[24];

  int* wsI = (int*)d_ws;
  float* wsF = (float*)d_ws;

  // Clear slot maps + counters (lists/features are only read where written)
  hipMemsetAsync(d_ws, 0, E_LIST0 * 4, stream);

  k_active0<<<(BDIM * NPIX + 255) / 256, 256, 0, stream>>>(
      x, wsI + E_MAP0, wsI + E_LIST0, wsI + E_CNT);
  k_y0<<<(BDIM * CAP0 * 32) / 256, 256, 0, stream>>>(
      x, w0, b0, g0, be0, wsI + E_LIST0, wsI + E_CNT, wsF + E_Y0);
  k_active1<<<(BDIM * G1N + 255) / 256, 256, 0, stream>>>(
      wsI + E_MAP0, wsI + E_MAP1, wsI + E_LIST1, wsI + E_CNT);
  k_y1<<<BDIM * CAP1, 64, 0, stream>>>(
      wsF + E_Y0, w1, b1, g1, be1, wsI + E_MAP0, wsI + E_LIST1, wsI + E_CNT, wsF + E_Y1);
  k_active2<<<(BDIM * G2N + 255) / 256, 256, 0, stream>>>(
      wsI + E_MAP1, wsI + E_LIST2, wsI + E_CNT);
  k_y2<<<BDIM * CAPM, 64, 0, stream>>>(
      wsF + E_Y1, w2, b2, g2, be2, wsI + E_MAP1, wsI + E_LIST2, wsI + E_CNT, wsF + E_FE);

  for (int layer = 0; layer < 2; ++layer) {
    k_qkv<<<BDIM * CAPM, 128, 0, stream>>>(
        wsF + E_FE, wsI + E_LIST2, wsI + E_CNT, wpe, bpe, wq, bq, wk, bk, wv, bv,
        layer, wsF + E_Q, wsF + E_K, wsF + E_V);
    k_attn<<<BDIM * NHEADS * (CAPM / 256), 256, 0, stream>>>(
        wsF + E_Q, wsF + E_K, wsF + E_V, wsI + E_CNT, wsF + E_O);
    k_proj<<<BDIM * CAPM, 64, 0, stream>>>(
        wsF + E_O, wo, bo, wsI + E_CNT, layer, wsF + E_FE);
  }

  k_head<<<BDIM, 64, 0, stream>>>(wsF + E_FE, wh, bh, wsI + E_CNT, (float*)d_out);
}

// Round 2
// 1481.932 us; speedup vs baseline: 1.0881x; 1.0881x over previous
//
#include <hip/hip_runtime.h>

// Problem constants
#define BDIM   8
#define NPIX   250000   // 500*500
#define G1N    62500    // 250*250
#define G2N    15625    // 125*125
#define CAP0   4096
#define CAP1   4096
#define CAPM   2048
#define CH     64
#define ACH    128
#define NHEADS 4
#define DH     32
#define KT     32       // attention key tile

static constexpr float BN_INV    = 0.99999500003749969f;   // 1/sqrt(1+1e-5)
static constexpr float ATT_SCALE = 0.17677669529663687f;   // 1/sqrt(32)

// Workspace element offsets (4-byte units)
static constexpr size_t E_MAP0  = 0;
static constexpr size_t E_MAP1  = E_MAP0 + (size_t)BDIM*NPIX;
static constexpr size_t E_CNT   = E_MAP1 + (size_t)BDIM*G1N;
static constexpr size_t E_LIST0 = E_CNT + 32;
static constexpr size_t E_LIST1 = E_LIST0 + (size_t)BDIM*CAP0;
static constexpr size_t E_LIST2 = E_LIST1 + (size_t)BDIM*CAP1;
static constexpr size_t E_Y0    = E_LIST2 + (size_t)BDIM*CAPM;
static constexpr size_t E_Y1    = E_Y0 + (size_t)BDIM*CAP0*32;
static constexpr size_t E_FE    = E_Y1 + (size_t)BDIM*CAP1*64;
static constexpr size_t E_Q     = E_FE + (size_t)BDIM*CAPM*64;
static constexpr size_t E_K     = E_Q + (size_t)BDIM*NHEADS*CAPM*DH;
static constexpr size_t E_V     = E_K + (size_t)BDIM*NHEADS*CAPM*DH;
static constexpr size_t E_O     = E_V + (size_t)BDIM*NHEADS*CAPM*DH;

__global__ void k_active0(const float* __restrict__ x, int* __restrict__ map0,
                          int* __restrict__ list0, int* __restrict__ cnt) {
  int idx = blockIdx.x * 256 + threadIdx.x;
  if (idx >= BDIM * NPIX) return;
  float v = x[idx];
  if (v != 0.f) {
    int b = idx / NPIX;
    int pix = idx - b * NPIX;
    int slot = atomicAdd(&cnt[b], 1);
    if (slot < CAP0) { list0[b * CAP0 + slot] = pix; map0[idx] = slot + 1; }
  }
}

__global__ void k_y0(const float* __restrict__ x, const float* __restrict__ w0,
                     const float* __restrict__ b0, const float* __restrict__ g0,
                     const float* __restrict__ be0,
                     const int* __restrict__ list0, const int* __restrict__ cnt,
                     float* __restrict__ y0) {
  int t = blockIdx.x * 256 + threadIdx.x;
  int b = t >> 17;
  int r = t & 131071;
  int slot = r >> 5, c = r & 31;
  int n = min(cnt[b], CAP0);
  if (slot >= n) return;
  int pix = list0[b * CAP0 + slot];
  int i = pix / 500, j = pix - i * 500;
  float acc = b0[c];
#pragma unroll
  for (int di = 0; di < 3; ++di) {
    int ii = i + di - 1;
    if ((unsigned)ii >= 500u) continue;
#pragma unroll
    for (int dj = 0; dj < 3; ++dj) {
      int jj = j + dj - 1;
      if ((unsigned)jj >= 500u) continue;
      acc += x[b * NPIX + ii * 500 + jj] * w0[(di * 3 + dj) * 32 + c];
    }
  }
  float o = g0[c] * acc * BN_INV + be0[c];
  y0[((size_t)(b * CAP0) + slot) * 32 + c] = fmaxf(o, 0.f);
}

__global__ void k_active1(const int* __restrict__ map0, int* __restrict__ map1,
                          int* __restrict__ list1, int* __restrict__ cnt) {
  int idx = blockIdx.x * 256 + threadIdx.x;
  if (idx >= BDIM * G1N) return;
  int b = idx / G1N;
  int p = idx - b * G1N;
  int i = p / 250, j = p - i * 250;
  const int* m = map0 + b * NPIX + (2 * i) * 500 + 2 * j;
  if (m[0] | m[1] | m[500] | m[501]) {
    int slot = atomicAdd(&cnt[BDIM + b], 1);
    if (slot < CAP1) { list1[b * CAP1 + slot] = p; map1[idx] = slot + 1; }
  }
}

// 8 sites per block, 64 threads (one per out-channel), transposed LDS staging
__global__ void k_y1(const float* __restrict__ y0, const float* __restrict__ w1,
                     const float* __restrict__ b1, const float* __restrict__ g1,
                     const float* __restrict__ be1,
                     const int* __restrict__ map0, const int* __restrict__ list1,
                     const int* __restrict__ cnt, float* __restrict__ y1) {
  int b = blockIdx.x >> 9;          // CAP1/8 = 512
  int sblk = blockIdx.x & 511;
  int s0 = sblk * 8;
  int n = min(cnt[BDIM + b], CAP1);
  if (s0 >= n) return;
  __shared__ float inT[4][32][8];   // [pp][ci][site]
  for (int idx = threadIdx.x; idx < 1024; idx += 64) {
    int s = idx & 7;
    int r = idx >> 3;
    int ci = r & 31, pp = r >> 5;
    float v = 0.f;
    int sg = s0 + s;
    if (sg < n) {
      int p = list1[b * CAP1 + sg];
      int i = p / 250, j = p - i * 250;
      int sm = map0[b * NPIX + (2 * i + (pp >> 1)) * 500 + (2 * j + (pp & 1))];
      if (sm) v = y0[((size_t)(b * CAP0) + (sm - 1)) * 32 + ci];
    }
    inT[pp][ci][s] = v;
  }
  __syncthreads();
  int co = threadIdx.x;
  float acc[8];
#pragma unroll
  for (int s = 0; s < 8; ++s) acc[s] = b1[co];
#pragma unroll 2
  for (int pp = 0; pp < 4; ++pp)
    for (int ci = 0; ci < 32; ++ci) {
      float wv = w1[((pp << 5) + ci) * 64 + co];
      float4 i0 = *(const float4*)&inT[pp][ci][0];
      float4 i1 = *(const float4*)&inT[pp][ci][4];
      acc[0] += i0.x * wv; acc[1] += i0.y * wv; acc[2] += i0.z * wv; acc[3] += i0.w * wv;
      acc[4] += i1.x * wv; acc[5] += i1.y * wv; acc[6] += i1.z * wv; acc[7] += i1.w * wv;
    }
  int smax = min(8, n - s0);
  for (int s = 0; s < smax; ++s) {
    float o = g1[co] * acc[s] * BN_INV + be1[co];
    y1[((size_t)(b * CAP1) + s0 + s) * 64 + co] = fmaxf(o, 0.f);
  }
}

__global__ void k_active2(const int* __restrict__ map1, int* __restrict__ list2,
                          int* __restrict__ cnt) {
  int idx = blockIdx.x * 256 + threadIdx.x;
  if (idx >= BDIM * G2N) return;
  int b = idx / G2N;
  int p = idx - b * G2N;
  int i = p / 125, j = p - i * 125;
  const int* m = map1 + b * G1N + (2 * i) * 250 + 2 * j;
  if (m[0] | m[1] | m[250] | m[251]) {
    int slot = atomicAdd(&cnt[2 * BDIM + b], 1);
    if (slot < CAPM) list2[b * CAPM + slot] = p;
  }
}

__global__ void k_y2(const float* __restrict__ y1, const float* __restrict__ w2,
                     const float* __restrict__ b2, const float* __restrict__ g2,
                     const float* __restrict__ be2,
                     const int* __restrict__ map1, const int* __restrict__ list2,
                     const int* __restrict__ cnt, float* __restrict__ feats) {
  int b = blockIdx.x >> 8;          // CAPM/8 = 256
  int sblk = blockIdx.x & 255;
  int s0 = sblk * 8;
  int n = min(cnt[2 * BDIM + b], CAPM);
  if (s0 >= n) return;
  __shared__ float inT[4][64][8];
  for (int idx = threadIdx.x; idx < 2048; idx += 64) {
    int s = idx & 7;
    int r = idx >> 3;
    int ci = r & 63, pp = r >> 6;
    float v = 0.f;
    int sg = s0 + s;
    if (sg < n) {
      int p = list2[b * CAPM + sg];
      int i = p / 125, j = p - i * 125;
      int sm = map1[b * G1N + (2 * i + (pp >> 1)) * 250 + (2 * j + (pp & 1))];
      if (sm) v = y1[((size_t)(b * CAP1) + (sm - 1)) * 64 + ci];
    }
    inT[pp][ci][s] = v;
  }
  __syncthreads();
  int co = threadIdx.x;
  float acc[8];
#pragma unroll
  for (int s = 0; s < 8; ++s) acc[s] = b2[co];
#pragma unroll 2
  for (int pp = 0; pp < 4; ++pp)
    for (int ci = 0; ci < 64; ++ci) {
      float wv = w2[((pp << 6) + ci) * 64 + co];
      float4 i0 = *(const float4*)&inT[pp][ci][0];
      float4 i1 = *(const float4*)&inT[pp][ci][4];
      acc[0] += i0.x * wv; acc[1] += i0.y * wv; acc[2] += i0.z * wv; acc[3] += i0.w * wv;
      acc[4] += i1.x * wv; acc[5] += i1.y * wv; acc[6] += i1.z * wv; acc[7] += i1.w * wv;
    }
  int smax = min(8, n - s0);
  for (int s = 0; s < smax; ++s) {
    float o = g2[co] * acc[s] * BN_INV + be2[co];
    feats[((size_t)(b * CAPM) + s0 + s) * 64 + co] = fmaxf(o, 0.f);
  }
}

// 16 sites per block, 128 threads (one per q/k/v out-channel)
__global__ void k_qkv(const float* __restrict__ feats, const int* __restrict__ list2,
                      const int* __restrict__ cnt,
                      const float* __restrict__ wpe, const float* __restrict__ bpe,
                      const float* __restrict__ wq, const float* __restrict__ bq,
                      const float* __restrict__ wk, const float* __restrict__ bk,
                      const float* __restrict__ wv, const float* __restrict__ bv,
                      int layer, float* __restrict__ qbuf, float* __restrict__ kbuf,
                      float* __restrict__ vbuf) {
  int b = blockIdx.x >> 7;          // CAPM/16 = 128
  int sblk = blockIdx.x & 127;
  int s0 = sblk * 16;
  int n = min(cnt[2 * BDIM + b], CAPM);
  if (s0 >= n) return;
  __shared__ float hT[64][16];
  for (int idx = threadIdx.x; idx < 1024; idx += 128) {
    int s = idx & 15, c = idx >> 4;
    float hv = 0.f;
    int sg = s0 + s;
    if (sg < n) {
      int p = list2[b * CAPM + sg];
      int i = p / 125, j = p - i * 125;
      hv = feats[((size_t)(b * CAPM) + sg) * 64 + c]
         + (float)i * (1.f / 125.f) * wpe[(layer * 2 + 0) * 64 + c]
         + (float)j * (1.f / 125.f) * wpe[(layer * 2 + 1) * 64 + c]
         + bpe[layer * 64 + c];
    }
    hT[c][s] = hv;
  }
  __syncthreads();
  int o = threadIdx.x;
  float accq[16], acck[16], accv[16];
  float bqv = bq[layer * 128 + o], bkv = bk[layer * 128 + o], bvv = bv[layer * 128 + o];
#pragma unroll
  for (int s = 0; s < 16; ++s) { accq[s] = bqv; acck[s] = bkv; accv[s] = bvv; }
  const float* wq_ = wq + (size_t)layer * 64 * 128 + o;
  const float* wk_ = wk + (size_t)layer * 64 * 128 + o;
  const float* wv_ = wv + (size_t)layer * 64 * 128 + o;
  for (int c = 0; c < 64; ++c) {
    float wqv = wq_[c * 128], wkv = wk_[c * 128], wvv = wv_[c * 128];
    float hh[16];
#pragma unroll
    for (int sq = 0; sq < 4; ++sq) {
      float4 h4 = *(const float4*)&hT[c][4 * sq];
      hh[4 * sq] = h4.x; hh[4 * sq + 1] = h4.y; hh[4 * sq + 2] = h4.z; hh[4 * sq + 3] = h4.w;
    }
#pragma unroll
    for (int s = 0; s < 16; ++s) {
      accq[s] += hh[s] * wqv; acck[s] += hh[s] * wkv; accv[s] += hh[s] * wvv;
    }
  }
  int hd = o >> 5, d = o & 31;
  int smax = min(16, n - s0);
  for (int s = 0; s < smax; ++s) {
    size_t base = (((size_t)(b * NHEADS + hd)) * CAPM + s0 + s) * DH + d;
    qbuf[base] = accq[s]; kbuf[base] = acck[s]; vbuf[base] = accv[s];
  }
}

// Flash attention: 64 queries/block, 4 waves split key tiles, LDS combine.
__global__ __launch_bounds__(256) void k_attn(const float* __restrict__ qbuf,
                                              const float* __restrict__ kbuf,
                                              const float* __restrict__ vbuf,
                                              const int* __restrict__ cnt,
                                              float* __restrict__ obuf) {
  int qblk = blockIdx.x & 31;        // CAPM/64 = 32
  int h = (blockIdx.x >> 5) & 3;
  int b = blockIdx.x >> 7;
  int n = min(cnt[2 * BDIM + b], CAPM);
  int q0 = qblk * 64;
  if (q0 >= n) return;
  int w = threadIdx.x >> 6, lane = threadIdx.x & 63;
  int qi = q0 + lane;
  bool qv = qi < n;
  size_t bh = (size_t)(b * NHEADS + h) * CAPM;

  __shared__ float lds[8704];        // union: tiles [4][2][32][32] / comb [4][64][34]
  float* Kt = lds + w * 2048;
  float* Vt = Kt + 1024;

  float q[32];
  if (qv) {
    const float4* qp = (const float4*)(qbuf + (bh + qi) * DH);
#pragma unroll
    for (int u = 0; u < 8; ++u) {
      float4 t = qp[u];
      q[4 * u] = t.x; q[4 * u + 1] = t.y; q[4 * u + 2] = t.z; q[4 * u + 3] = t.w;
    }
  } else {
#pragma unroll
    for (int u = 0; u < 32; ++u) q[u] = 0.f;
  }
  float m = -1e30f, l = 0.f;
  float acc[32];
#pragma unroll
  for (int u = 0; u < 32; ++u) acc[u] = 0.f;

  int nt = (n + KT - 1) / KT;
  int iters = (nt + 3) >> 2;
  for (int it = 0; it < iters; ++it) {
    int t = it * 4 + w;
    __syncthreads();
    if (t < nt) {
      int k0 = t * KT;
      int kk = lane >> 1, half = lane & 1;
      int kg = k0 + kk;
      float* kd = Kt + kk * 32 + half * 16;
      float* vd = Vt + kk * 32 + half * 16;
      if (kg < n) {
        const float* kp = kbuf + (bh + kg) * DH + half * 16;
        const float* vp = vbuf + (bh + kg) * DH + half * 16;
#pragma unroll
        for (int u = 0; u < 4; ++u) {
          *(float4*)(kd + 4 * u) = *(const float4*)(kp + 4 * u);
          *(float4*)(vd + 4 * u) = *(const float4*)(vp + 4 * u);
        }
      } else {
        float4 z = make_float4(0.f, 0.f, 0.f, 0.f);
#pragma unroll
        for (int u = 0; u < 4; ++u) { *(float4*)(kd + 4 * u) = z; *(float4*)(vd + 4 * u) = z; }
      }
    }
    __syncthreads();
    if (t < nt) {
      int kmax = n - t * KT;     // >=1
      float s[KT];
#pragma unroll 4
      for (int kk = 0; kk < KT; ++kk) {
        const float4* kr = (const float4*)(Kt + kk * 32);
        float sv = 0.f;
#pragma unroll
        for (int u = 0; u < 8; ++u) {
          float4 kv = kr[u];
          sv += q[4 * u] * kv.x + q[4 * u + 1] * kv.y + q[4 * u + 2] * kv.z + q[4 * u + 3] * kv.w;
        }
        s[kk] = sv;
      }
      float tmax = -1e30f;
#pragma unroll
      for (int kk = 0; kk < KT; ++kk) {
        s[kk] = (kk < kmax) ? s[kk] * ATT_SCALE : -1e30f;
        tmax = fmaxf(tmax, s[kk]);
      }
      float mn = fmaxf(m, tmax);
      float f1 = __expf(m - mn);
      m = mn;
      l *= f1;
#pragma unroll
      for (int u = 0; u < 32; ++u) acc[u] *= f1;
#pragma unroll 4
      for (int kk = 0; kk < KT; ++kk) {
        float p = __expf(s[kk] - mn);
        l += p;
        const float4* vr = (const float4*)(Vt + kk * 32);
#pragma unroll
        for (int u = 0; u < 8; ++u) {
          float4 vv = vr[u];
          acc[4 * u]     += p * vv.x;
          acc[4 * u + 1] += p * vv.y;
          acc[4 * u + 2] += p * vv.z;
          acc[4 * u + 3] += p * vv.w;
        }
      }
    }
  }
  // write partials (overlaps tile region -> sync both sides)
  __syncthreads();
  float* cb = lds + (w * 64 + lane) * 34;
  cb[0] = m; cb[1] = l;
#pragma unroll
  for (int u = 0; u < 32; ++u) cb[2 + u] = acc[u];
  __syncthreads();
  // combine: thread = (query qq, channel-octet part)
  int qq = threadIdx.x & 63, part = threadIdx.x >> 6;
  const float* c0 = lds + qq * 34;
  const float* c1 = lds + (64 + qq) * 34;
  const float* c2 = lds + (128 + qq) * 34;
  const float* c3 = lds + (192 + qq) * 34;
  float m0 = c0[0], m1 = c1[0], m2 = c2[0], m3 = c3[0];
  float ms = fmaxf(fmaxf(m0, m1), fmaxf(m2, m3));
  float e0 = __expf(m0 - ms), e1 = __expf(m1 - ms), e2 = __expf(m2 - ms), e3 = __expf(m3 - ms);
  float lt = e0 * c0[1] + e1 * c1[1] + e2 * c2[1] + e3 * c3[1];
  float inv = 1.f / lt;
  int qg = q0 + qq;
  if (qg < n) {
    const float* a0 = c0 + 2 + part * 8;
    const float* a1 = c1 + 2 + part * 8;
    const float* a2 = c2 + 2 + part * 8;
    const float* a3 = c3 + 2 + part * 8;
    float* op = obuf + ((size_t)b * CAPM + qg) * ACH + h * DH + part * 8;
    float4 r0, r1;
    r0.x = (e0 * a0[0] + e1 * a1[0] + e2 * a2[0] + e3 * a3[0]) * inv;
    r0.y = (e0 * a0[1] + e1 * a1[1] + e2 * a2[1] + e3 * a3[1]) * inv;
    r0.z = (e0 * a0[2] + e1 * a1[2] + e2 * a2[2] + e3 * a3[2]) * inv;
    r0.w = (e0 * a0[3] + e1 * a1[3] + e2 * a2[3] + e3 * a3[3]) * inv;
    r1.x = (e0 * a0[4] + e1 * a1[4] + e2 * a2[4] + e3 * a3[4]) * inv;
    r1.y = (e0 * a0[5] + e1 * a1[5] + e2 * a2[5] + e3 * a3[5]) * inv;
    r1.z = (e0 * a0[6] + e1 * a1[6] + e2 * a2[6] + e3 * a3[6]) * inv;
    r1.w = (e0 * a0[7] + e1 * a1[7] + e2 * a2[7] + e3 * a3[7]) * inv;
    *(float4*)op = r0;
    *(float4*)(op + 4) = r1;
  }
}

// 16 sites per block, 64 threads
__global__ void k_proj(const float* __restrict__ obuf, const float* __restrict__ wo,
                       const float* __restrict__ bo, const int* __restrict__ cnt,
                       int layer, float* __restrict__ feats) {
  int b = blockIdx.x >> 7;          // CAPM/16 = 128
  int sblk = blockIdx.x & 127;
  int s0 = sblk * 16;
  int n = min(cnt[2 * BDIM + b], CAPM);
  if (s0 >= n) return;
  __shared__ float oT[128][16];
  for (int idx = threadIdx.x; idx < 2048; idx += 64) {
    int s = idx & 15, c = idx >> 4;
    int sg = s0 + s;
    oT[c][s] = (sg < n) ? obuf[((size_t)b * CAPM + sg) * ACH + c] : 0.f;
  }
  __syncthreads();
  int co = threadIdx.x;
  float acc[16];
#pragma unroll
  for (int s = 0; s < 16; ++s) acc[s] = 0.f;
  const float* w = wo + (size_t)layer * 128 * 64 + co;
  for (int c = 0; c < 128; ++c) {
    float wv = w[c * 64];
    float hh[16];
#pragma unroll
    for (int sq = 0; sq < 4; ++sq) {
      float4 h4 = *(const float4*)&oT[c][4 * sq];
      hh[4 * sq] = h4.x; hh[4 * sq + 1] = h4.y; hh[4 * sq + 2] = h4.z; hh[4 * sq + 3] = h4.w;
    }
#pragma unroll
    for (int s = 0; s < 16; ++s) acc[s] += hh[s] * wv;
  }
  float bov = bo[layer * 64 + co];
  int smax = min(16, n - s0);
  for (int s = 0; s < smax; ++s)
    feats[((size_t)(b * CAPM) + s0 + s) * 64 + co] += acc[s] + bov;
}

__global__ void k_head(const float* __restrict__ feats, const float* __restrict__ wh,
                       const float* __restrict__ bh, const int* __restrict__ cnt,
                       float* __restrict__ out) {
  int b = blockIdx.x;
  int n = min(cnt[2 * BDIM + b], CAPM);
  int c = threadIdx.x;
  float s = 0.f;
  for (int mm = 0; mm < n; ++mm) s += feats[((size_t)(b * CAPM) + mm) * 64 + c];
  __shared__ float pooled[64];
  pooled[c] = s / (float)max(n, 1);
  __syncthreads();
  if (c < 4) {
    float o = bh[c];
#pragma unroll
    for (int c2 = 0; c2 < 64; ++c2) o += pooled[c2] * wh[c2 * 4 + c];
    out[b * 4 + c] = o;
  }
}

extern "C" void kernel_launch(void* const* d_in, const int* in_sizes, int n_in,
                              void* d_out, int out_size, void* d_ws, size_t ws_size,
                              hipStream_t stream) {
  const float* x   = (const float*)d_in[0];
  const float* w0  = (const float*)d_in[1];
  const float* b0  = (const float*)d_in[2];
  const float* g0  = (const float*)d_in[3];
  const float* be0 = (const float*)d_in[4];
  const float* w1  = (const float*)d_in[5];
  const float* b1  = (const float*)d_in[6];
  const float* g1  = (const float*)d_in[7];
  const float* be1 = (const float*)d_in[8];
  const float* w2  = (const float*)d_in[9];
  const float* b2  = (const float*)d_in[10];
  const float* g2  = (const float*)d_in[11];
  const float* be2 = (const float*)d_in[12];
  const float* wpe = (const float*)d_in[13];
  const float* bpe = (const float*)d_in[14];
  const float* wq  = (const float*)d_in[15];
  const float* bq  = (const float*)d_in[16];
  const float* wk  = (const float*)d_in[17];
  const float* bk  = (const float*)d_in[18];
  const float* wv  = (const float*)d_in[19];
  const float* bv  = (const float*)d_in[20];
  const float* wo  = (const float*)d_in[21];
  const float* bo  = (const float*)d_in[22];
  const float* wh  = (const float*)d_in[23];
  const float* bh  = (const float*)d_in[24];

  int* wsI = (int*)d_ws;
  float* wsF = (float*)d_ws;

  hipMemsetAsync(d_ws, 0, E_LIST0 * 4, stream);

  k_active0<<<(BDIM * NPIX + 255) / 256, 256, 0, stream>>>(
      x, wsI + E_MAP0, wsI + E_LIST0, wsI + E_CNT);
  k_y0<<<(BDIM * CAP0 * 32) / 256, 256, 0, stream>>>(
      x, w0, b0, g0, be0, wsI + E_LIST0, wsI + E_CNT, wsF + E_Y0);
  k_active1<<<(BDIM * G1N + 255) / 256, 256, 0, stream>>>(
      wsI + E_MAP0, wsI + E_MAP1, wsI + E_LIST1, wsI + E_CNT);
  k_y1<<<BDIM * (CAP1 / 8), 64, 0, stream>>>(
      wsF + E_Y0, w1, b1, g1, be1, wsI + E_MAP0, wsI + E_LIST1, wsI + E_CNT, wsF + E_Y1);
  k_active2<<<(BDIM * G2N + 255) / 256, 256, 0, stream>>>(
      wsI + E_MAP1, wsI + E_LIST2, wsI + E_CNT);
  k_y2<<<BDIM * (CAPM / 8), 64, 0, stream>>>(
      wsF + E_Y1, w2, b2, g2, be2, wsI + E_MAP1, wsI + E_LIST2, wsI + E_CNT, wsF + E_FE);

  for (int layer = 0; layer < 2; ++layer) {
    k_qkv<<<BDIM * (CAPM / 16), 128, 0, stream>>>(
        wsF + E_FE, wsI + E_LIST2, wsI + E_CNT, wpe, bpe, wq, bq, wk, bk, wv, bv,
        layer, wsF + E_Q, wsF + E_K, wsF + E_V);
    k_attn<<<BDIM * NHEADS * (CAPM / 64), 256, 0, stream>>>(
        wsF + E_Q, wsF + E_K, wsF + E_V, wsI + E_CNT, wsF + E_O);
    k_proj<<<BDIM * (CAPM / 16), 64, 0, stream>>>(
        wsF + E_O, wo, bo, wsI + E_CNT, layer, wsF + E_FE);
  }

  k_head<<<BDIM, 64, 0, stream>>>(wsF + E_FE, wh, bh, wsI + E_CNT, (float*)d_out);
}

// Round 4
// 392.973 us; speedup vs baseline: 4.1034x; 3.7711x over previous
//
#include <hip/hip_runtime.h>

// Problem constants
#define BDIM   8
#define NPIX   250000   // 500*500
#define G1N    62500    // 250*250
#define G2N    15625    // 125*125
#define NB0    977      // ceil(NPIX/256)
#define NB1    245      // ceil(G1N/256)
#define NB2    62       // ceil(G2N/256)
#define CAP0   4096
#define CAP1   4096
#define CAPM   2048
#define CH     64
#define ACH    128
#define NHEADS 4
#define DH     32

static constexpr float BN_INV    = 0.99999500003749969f;   // 1/sqrt(1+1e-5)
static constexpr float ATT_SCALE = 0.17677669529663687f;   // 1/sqrt(32)

typedef _Float16 f16x8 __attribute__((ext_vector_type(8)));
typedef float f32x4 __attribute__((ext_vector_type(4)));

// Workspace word offsets (4-byte units). Zeroed prefix: [0, E_ZEND)
static constexpr size_t E_MAP0  = 0;                                  // int [B*NPIX]
static constexpr size_t E_MAP1  = E_MAP0 + (size_t)BDIM*NPIX;         // int [B*G1N]
static constexpr size_t E_CNT   = E_MAP1 + (size_t)BDIM*G1N;          // int [32]
static constexpr size_t E_ZEND  = E_CNT + 32;
static constexpr size_t E_BC    = E_ZEND;                             // int [3][B][1024]
static constexpr size_t E_BO    = E_BC + (size_t)3*BDIM*1024;         // int [3][B][1024]
static constexpr size_t E_LIST0 = E_BO + (size_t)3*BDIM*1024;         // int [B*CAP0]
static constexpr size_t E_LIST1 = E_LIST0 + (size_t)BDIM*CAP0;
static constexpr size_t E_LIST2 = E_LIST1 + (size_t)BDIM*CAP1;
static constexpr size_t E_Y0    = E_LIST2 + (size_t)BDIM*CAPM;        // f32 [B*CAP0*32]
static constexpr size_t E_Y1    = E_Y0 + (size_t)BDIM*CAP0*32;       // f32 [B*CAP1*64]
static constexpr size_t E_FE    = E_Y1 + (size_t)BDIM*CAP1*64;       // f32 [B*CAPM*64]
static constexpr size_t E_QF    = E_FE + (size_t)BDIM*CAPM*64;       // f16 [32bh][CAPM][32]
static constexpr size_t E_KF    = E_QF + (size_t)32*CAPM*32/2;
static constexpr size_t E_VT    = E_KF + (size_t)32*CAPM*32/2;       // f16 [32bh][32][CAPM]
static constexpr size_t E_O     = E_VT + (size_t)32*CAPM*32/2;       // f32 [B*CAPM*128]

// ---------------- deterministic compaction: count / scan / emit --------------

__device__ __forceinline__ bool act0(const float* x, int pix, int b) {
  return (pix < NPIX) && (x[(size_t)b * NPIX + pix] != 0.f);
}
__device__ __forceinline__ bool act1(const int* map0, int p, int b) {
  if (p >= G1N) return false;
  int i = p / 250, j = p - i * 250;
  const int* m = map0 + (size_t)b * NPIX + (2 * i) * 500 + 2 * j;
  return (m[0] | m[1] | m[500] | m[501]) != 0;
}
__device__ __forceinline__ bool act2(const int* map1, int p, int b) {
  if (p >= G2N) return false;
  int i = p / 125, j = p - i * 125;
  const int* m = map1 + (size_t)b * G1N + (2 * i) * 250 + 2 * j;
  return (m[0] | m[1] | m[250] | m[251]) != 0;
}

#define COUNT_BODY(ACT_EXPR)                                            \
  int idx = blockIdx.x * 256 + threadIdx.x;                             \
  int b = blockIdx.y;                                                   \
  bool act = (ACT_EXPR);                                                \
  unsigned long long mask = __ballot(act);                              \
  __shared__ int wc[4];                                                 \
  if ((threadIdx.x & 63) == 0) wc[threadIdx.x >> 6] = __popcll(mask);   \
  __syncthreads();                                                      \
  if (threadIdx.x == 0)                                                 \
    bcnt[b * 1024 + blockIdx.x] = wc[0] + wc[1] + wc[2] + wc[3];

__global__ void k_cnt0(const float* __restrict__ x, int* __restrict__ bcnt) {
  COUNT_BODY(act0(x, idx, b))
}
__global__ void k_cnt1(const int* __restrict__ map0, int* __restrict__ bcnt) {
  COUNT_BODY(act1(map0, idx, b))
}
__global__ void k_cnt2(const int* __restrict__ map1, int* __restrict__ bcnt) {
  COUNT_BODY(act2(map1, idx, b))
}

// one block per image; nblk <= 1024. Exclusive block offsets + total count.
__global__ __launch_bounds__(1024) void k_scan(const int* __restrict__ bcnt,
                                               int* __restrict__ boff,
                                               int* __restrict__ cnt,
                                               int nblk, int cbase) {
  int b = blockIdx.x;
  __shared__ int tmp[1024];
  int t = threadIdx.x;
  int v = (t < nblk) ? bcnt[b * 1024 + t] : 0;
  tmp[t] = v;
  __syncthreads();
  for (int off = 1; off < 1024; off <<= 1) {
    int add = (t >= off) ? tmp[t - off] : 0;
    __syncthreads();
    tmp[t] += add;
    __syncthreads();
  }
  if (t < nblk) boff[b * 1024 + t] = tmp[t] - v;
  if (t == nblk - 1) cnt[cbase + b] = tmp[t];
}

#define EMIT_PROLOG(ACT_EXPR)                                           \
  int idx = blockIdx.x * 256 + threadIdx.x;                             \
  int b = blockIdx.y;                                                   \
  bool act = (ACT_EXPR);                                                \
  unsigned long long mask = __ballot(act);                              \
  __shared__ int wbase[4];                                              \
  if ((threadIdx.x & 63) == 0) wbase[threadIdx.x >> 6] = __popcll(mask);\
  __syncthreads();                                                      \
  if (threadIdx.x == 0) {                                               \
    int s = boff[b * 1024 + blockIdx.x];                                \
    for (int w = 0; w < 4; ++w) { int c = wbase[w]; wbase[w] = s; s += c; } \
  }                                                                     \
  __syncthreads();                                                      \
  int lane = threadIdx.x & 63;                                          \
  int slot = wbase[threadIdx.x >> 6] + __popcll(mask & ((1ull << lane) - 1ull));

__global__ void k_emit0(const float* __restrict__ x, const int* __restrict__ boff,
                        int* __restrict__ map0, int* __restrict__ list0) {
  EMIT_PROLOG(act0(x, idx, b))
  if (act && slot < CAP0) {
    list0[b * CAP0 + slot] = idx;
    map0[(size_t)b * NPIX + idx] = slot + 1;
  }
}
__global__ void k_emit1(const int* __restrict__ map0, const int* __restrict__ boff,
                        int* __restrict__ map1, int* __restrict__ list1) {
  EMIT_PROLOG(act1(map0, idx, b))
  if (act && slot < CAP1) {
    list1[b * CAP1 + slot] = idx;
    map1[(size_t)b * G1N + idx] = slot + 1;
  }
}
__global__ void k_emit2(const int* __restrict__ map1, const int* __restrict__ boff,
                        int* __restrict__ list2) {
  EMIT_PROLOG(act2(map1, idx, b))
  if (act && slot < CAPM) list2[b * CAPM + slot] = idx;
}

// ---------------- sparse convs -----------------------------------------------

__global__ void k_y0(const float* __restrict__ x, const float* __restrict__ w0,
                     const float* __restrict__ b0, const float* __restrict__ g0,
                     const float* __restrict__ be0,
                     const int* __restrict__ list0, const int* __restrict__ cnt,
                     float* __restrict__ y0) {
  int t = blockIdx.x * 256 + threadIdx.x;
  int b = t >> 17;
  int r = t & 131071;
  int slot = r >> 5, c = r & 31;
  int n = min(cnt[b], CAP0);
  if (slot >= n) return;
  int pix = list0[b * CAP0 + slot];
  int i = pix / 500, j = pix - i * 500;
  float acc = b0[c];
#pragma unroll
  for (int di = 0; di < 3; ++di) {
    int ii = i + di - 1;
    if ((unsigned)ii >= 500u) continue;
#pragma unroll
    for (int dj = 0; dj < 3; ++dj) {
      int jj = j + dj - 1;
      if ((unsigned)jj >= 500u) continue;
      acc += x[(size_t)b * NPIX + ii * 500 + jj] * w0[(di * 3 + dj) * 32 + c];
    }
  }
  float o = g0[c] * acc * BN_INV + be0[c];
  y0[((size_t)(b * CAP0) + slot) * 32 + c] = fmaxf(o, 0.f);
}

__global__ void k_y1(const float* __restrict__ y0, const float* __restrict__ w1,
                     const float* __restrict__ b1, const float* __restrict__ g1,
                     const float* __restrict__ be1,
                     const int* __restrict__ map0, const int* __restrict__ list1,
                     const int* __restrict__ cnt, float* __restrict__ y1) {
  int b = blockIdx.x >> 9;          // CAP1/8 = 512
  int sblk = blockIdx.x & 511;
  int s0 = sblk * 8;
  int n = min(cnt[BDIM + b], CAP1);
  if (s0 >= n) return;
  __shared__ float inT[4][32][8];
  for (int idx = threadIdx.x; idx < 1024; idx += 64) {
    int s = idx & 7;
    int r = idx >> 3;
    int ci = r & 31, pp = r >> 5;
    float v = 0.f;
    int sg = s0 + s;
    if (sg < n) {
      int p = list1[b * CAP1 + sg];
      int i = p / 250, j = p - i * 250;
      int sm = map0[(size_t)b * NPIX + (2 * i + (pp >> 1)) * 500 + (2 * j + (pp & 1))];
      if (sm) v = y0[((size_t)(b * CAP0) + (sm - 1)) * 32 + ci];
    }
    inT[pp][ci][s] = v;
  }
  __syncthreads();
  int co = threadIdx.x;
  float acc[8];
#pragma unroll
  for (int s = 0; s < 8; ++s) acc[s] = b1[co];
#pragma unroll 2
  for (int pp = 0; pp < 4; ++pp)
    for (int ci = 0; ci < 32; ++ci) {
      float wv = w1[((pp << 5) + ci) * 64 + co];
      float4 i0 = *(const float4*)&inT[pp][ci][0];
      float4 i1 = *(const float4*)&inT[pp][ci][4];
      acc[0] += i0.x * wv; acc[1] += i0.y * wv; acc[2] += i0.z * wv; acc[3] += i0.w * wv;
      acc[4] += i1.x * wv; acc[5] += i1.y * wv; acc[6] += i1.z * wv; acc[7] += i1.w * wv;
    }
  int smax = min(8, n - s0);
  for (int s = 0; s < smax; ++s) {
    float o = g1[co] * acc[s] * BN_INV + be1[co];
    y1[((size_t)(b * CAP1) + s0 + s) * 64 + co] = fmaxf(o, 0.f);
  }
}

__global__ void k_y2(const float* __restrict__ y1, const float* __restrict__ w2,
                     const float* __restrict__ b2, const float* __restrict__ g2,
                     const float* __restrict__ be2,
                     const int* __restrict__ map1, const int* __restrict__ list2,
                     const int* __restrict__ cnt, float* __restrict__ feats) {
  int b = blockIdx.x >> 8;          // CAPM/8 = 256
  int sblk = blockIdx.x & 255;
  int s0 = sblk * 8;
  int n = min(cnt[2 * BDIM + b], CAPM);
  if (s0 >= n) return;
  __shared__ float inT[4][64][8];
  for (int idx = threadIdx.x; idx < 2048; idx += 64) {
    int s = idx & 7;
    int r = idx >> 3;
    int ci = r & 63, pp = r >> 6;
    float v = 0.f;
    int sg = s0 + s;
    if (sg < n) {
      int p = list2[b * CAPM + sg];
      int i = p / 125, j = p - i * 125;
      int sm = map1[(size_t)b * G1N + (2 * i + (pp >> 1)) * 250 + (2 * j + (pp & 1))];
      if (sm) v = y1[((size_t)(b * CAP1) + (sm - 1)) * 64 + ci];
    }
    inT[pp][ci][s] = v;
  }
  __syncthreads();
  int co = threadIdx.x;
  float acc[8];
#pragma unroll
  for (int s = 0; s < 8; ++s) acc[s] = b2[co];
#pragma unroll 2
  for (int pp = 0; pp < 4; ++pp)
    for (int ci = 0; ci < 64; ++ci) {
      float wv = w2[((pp << 6) + ci) * 64 + co];
      float4 i0 = *(const float4*)&inT[pp][ci][0];
      float4 i1 = *(const float4*)&inT[pp][ci][4];
      acc[0] += i0.x * wv; acc[1] += i0.y * wv; acc[2] += i0.z * wv; acc[3] += i0.w * wv;
      acc[4] += i1.x * wv; acc[5] += i1.y * wv; acc[6] += i1.z * wv; acc[7] += i1.w * wv;
    }
  int smax = min(8, n - s0);
  for (int s = 0; s < smax; ++s) {
    float o = g2[co] * acc[s] * BN_INV + be2[co];
    feats[((size_t)(b * CAPM) + s0 + s) * 64 + co] = fmaxf(o, 0.f);
  }
}

// ---------------- QKV projection -> f16 buffers ------------------------------

__global__ void k_qkv(const float* __restrict__ feats, const int* __restrict__ list2,
                      const int* __restrict__ cnt,
                      const float* __restrict__ wpe, const float* __restrict__ bpe,
                      const float* __restrict__ wq, const float* __restrict__ bq,
                      const float* __restrict__ wk, const float* __restrict__ bk,
                      const float* __restrict__ wv, const float* __restrict__ bv,
                      int layer, _Float16* __restrict__ qf, _Float16* __restrict__ kf,
                      _Float16* __restrict__ vt) {
  int b = blockIdx.x >> 7;          // CAPM/16 = 128
  int sblk = blockIdx.x & 127;
  int s0 = sblk * 16;
  int n = min(cnt[2 * BDIM + b], CAPM);
  if (s0 >= n) return;
  __shared__ float hT[64][16];
  for (int idx = threadIdx.x; idx < 1024; idx += 128) {
    int s = idx & 15, c = idx >> 4;
    float hv = 0.f;
    int sg = s0 + s;
    if (sg < n) {
      int p = list2[b * CAPM + sg];
      int i = p / 125, j = p - i * 125;
      hv = feats[((size_t)(b * CAPM) + sg) * 64 + c]
         + (float)i * (1.f / 125.f) * wpe[(layer * 2 + 0) * 64 + c]
         + (float)j * (1.f / 125.f) * wpe[(layer * 2 + 1) * 64 + c]
         + bpe[layer * 64 + c];
    }
    hT[c][s] = hv;
  }
  __syncthreads();
  int o = threadIdx.x;
  float accq[16], acck[16], accv[16];
  float bqv = bq[layer * 128 + o], bkv = bk[layer * 128 + o], bvv = bv[layer * 128 + o];
#pragma unroll
  for (int s = 0; s < 16; ++s) { accq[s] = bqv; acck[s] = bkv; accv[s] = bvv; }
  const float* wq_ = wq + (size_t)layer * 64 * 128 + o;
  const float* wk_ = wk + (size_t)layer * 64 * 128 + o;
  const float* wv_ = wv + (size_t)layer * 64 * 128 + o;
  for (int c = 0; c < 64; ++c) {
    float wqv = wq_[c * 128], wkv = wk_[c * 128], wvv = wv_[c * 128];
    float hh[16];
#pragma unroll
    for (int sq = 0; sq < 4; ++sq) {
      float4 h4 = *(const float4*)&hT[c][4 * sq];
      hh[4 * sq] = h4.x; hh[4 * sq + 1] = h4.y; hh[4 * sq + 2] = h4.z; hh[4 * sq + 3] = h4.w;
    }
#pragma unroll
    for (int s = 0; s < 16; ++s) {
      accq[s] += hh[s] * wqv; acck[s] += hh[s] * wkv; accv[s] += hh[s] * wvv;
    }
  }
  int hd = o >> 5, d = o & 31;
  size_t bh = (size_t)(b * NHEADS + hd);
  int smax = min(16, n - s0);
  for (int s = 0; s < smax; ++s) {
    size_t rb = (bh * CAPM + s0 + s) * 32 + d;
    qf[rb] = (_Float16)accq[s];
    kf[rb] = (_Float16)acck[s];
    vt[(bh * 32 + d) * CAPM + s0 + s] = (_Float16)accv[s];
  }
}

// ---------------- MFMA flash attention ---------------------------------------
// One wave / 16-query tile. S^T = K·Q^T (D rows=keys, cols=queries=qr).
// Softmax state (m,l,f) lives per column qr; PV output rows are query 4g+r,
// so per-tile f and final l are TRANSPOSED through LDS (Lf/Ll) to match rows.
// P bounced via 2KB XOR-swizzled LDS. l summed from f16-ROUNDED P for
// numerator/denominator consistency. Padded keys: p == 0.0 exactly, and all
// workspace garbage is finite (0xAA poison / our own writes), so 0*V == 0.

union U4H8 { uint4 u; f16x8 h; };
union PKU  { _Float16 h[2]; unsigned int u; };

__global__ __launch_bounds__(64) void k_attn(
    const _Float16* __restrict__ qf, const _Float16* __restrict__ kf,
    const _Float16* __restrict__ vt, const int* __restrict__ cnt,
    float* __restrict__ obuf) {
  int qt = blockIdx.x & 127;          // CAPM/16
  int h  = (blockIdx.x >> 7) & 3;
  int b  = blockIdx.x >> 9;
  int n = min(cnt[2 * BDIM + b], CAPM);
  int q0 = qt * 16;
  if (q0 >= n) return;
  int lane = threadIdx.x;
  int g = lane >> 4, qr = lane & 15;
  size_t bh = (size_t)(b * NHEADS + h) * CAPM;
  f16x8 fq = *(const f16x8*)(qf + (bh + q0 + qr) * 32 + g * 8);   // Q B-frag
  f32x4 acc0 = {0.f, 0.f, 0.f, 0.f}, acc1 = {0.f, 0.f, 0.f, 0.f};
  float m = -1e30f, l = 0.f;
  __shared__ unsigned int P[512];     // 16q x 64k f16, XOR-swizzled
  __shared__ float Lf[16];
  __shared__ float Ll[16];
  int swz = (qr & 7) << 2;
  const _Float16* vbase = vt + (size_t)(b * NHEADS + h) * 32 * CAPM;

  for (int t0 = 0; t0 < n; t0 += 64) {
    f32x4 st[4];
#pragma unroll
    for (int t = 0; t < 4; ++t) {
      f16x8 ka = *(const f16x8*)(kf + (bh + t0 + 16 * t + qr) * 32 + g * 8);
      f32x4 z = {0.f, 0.f, 0.f, 0.f};
      st[t] = __builtin_amdgcn_mfma_f32_16x16x32_f16(ka, fq, z, 0, 0, 0);
    }
    if (t0 + 64 > n) {                 // tail: mask keys >= n
#pragma unroll
      for (int t = 0; t < 4; ++t)
#pragma unroll
        for (int r = 0; r < 4; ++r)
          if (t0 + 16 * t + 4 * g + r >= n) st[t][r] = -1e30f;
    }
    float tm = -1e30f;
#pragma unroll
    for (int t = 0; t < 4; ++t)
#pragma unroll
      for (int r = 0; r < 4; ++r) tm = fmaxf(tm, st[t][r]);
    tm = fmaxf(tm, __shfl_xor(tm, 16));
    tm = fmaxf(tm, __shfl_xor(tm, 32));
    float mn = fmaxf(m, tm * ATT_SCALE);
    float f = __expf(m - mn);          // rescale factor for query qr
    m = mn;
    if (g == 0) Lf[qr] = f;
    float ls = 0.f;
#pragma unroll
    for (int t = 0; t < 4; ++t) {
      PKU a, c;
      float p0 = __expf(st[t][0] * ATT_SCALE - mn);
      float p1 = __expf(st[t][1] * ATT_SCALE - mn);
      float p2 = __expf(st[t][2] * ATT_SCALE - mn);
      float p3 = __expf(st[t][3] * ATT_SCALE - mn);
      a.h[0] = (_Float16)p0; a.h[1] = (_Float16)p1;
      c.h[0] = (_Float16)p2; c.h[1] = (_Float16)p3;
      ls += (float)a.h[0] + (float)a.h[1] + (float)c.h[0] + (float)c.h[1];
      int w = qr * 32 + 8 * t + 2 * g;
      P[w ^ swz] = a.u;
      P[(w + 1) ^ swz] = c.u;
    }
    ls += __shfl_xor(ls, 16);
    ls += __shfl_xor(ls, 32);
    l = l * f + ls;
    __syncthreads();                   // P + Lf visible
    U4H8 pa0, pa1;                     // A-frags: row=query qr, keys 8g.. (+32)
    pa0.u = *(const uint4*)&P[(qr * 32 + 4 * g) ^ swz];
    pa1.u = *(const uint4*)&P[(qr * 32 + 16 + 4 * g) ^ swz];
    float fr0 = Lf[4 * g + 0], fr1 = Lf[4 * g + 1];
    float fr2 = Lf[4 * g + 2], fr3 = Lf[4 * g + 3];
    acc0[0] *= fr0; acc0[1] *= fr1; acc0[2] *= fr2; acc0[3] *= fr3;
    acc1[0] *= fr0; acc1[1] *= fr1; acc1[2] *= fr2; acc1[3] *= fr3;
    __syncthreads();                   // protect P/Lf for next iter
    f16x8 v00 = *(const f16x8*)(vbase + (size_t)qr * CAPM + t0 + g * 8);
    f16x8 v01 = *(const f16x8*)(vbase + (size_t)(16 + qr) * CAPM + t0 + g * 8);
    f16x8 v10 = *(const f16x8*)(vbase + (size_t)qr * CAPM + t0 + 32 + g * 8);
    f16x8 v11 = *(const f16x8*)(vbase + (size_t)(16 + qr) * CAPM + t0 + 32 + g * 8);
    acc0 = __builtin_amdgcn_mfma_f32_16x16x32_f16(pa0.h, v00, acc0, 0, 0, 0);
    acc1 = __builtin_amdgcn_mfma_f32_16x16x32_f16(pa0.h, v01, acc1, 0, 0, 0);
    acc0 = __builtin_amdgcn_mfma_f32_16x16x32_f16(pa1.h, v10, acc0, 0, 0, 0);
    acc1 = __builtin_amdgcn_mfma_f32_16x16x32_f16(pa1.h, v11, acc1, 0, 0, 0);
  }
  if (g == 0) Ll[qr] = l;
  __syncthreads();
#pragma unroll
  for (int r = 0; r < 4; ++r) {
    int tok = q0 + 4 * g + r;
    if (tok < n) {
      float inv = 1.f / Ll[4 * g + r];
      float* op = obuf + ((size_t)b * CAPM + tok) * ACH + h * DH;
      op[qr] = acc0[r] * inv;
      op[16 + qr] = acc1[r] * inv;
    }
  }
}

// ---------------- output projection + residual -------------------------------

__global__ void k_proj(const float* __restrict__ obuf, const float* __restrict__ wo,
                       const float* __restrict__ bo, const int* __restrict__ cnt,
                       int layer, float* __restrict__ feats) {
  int b = blockIdx.x >> 7;          // CAPM/16 = 128
  int sblk = blockIdx.x & 127;
  int s0 = sblk * 16;
  int n = min(cnt[2 * BDIM + b], CAPM);
  if (s0 >= n) return;
  __shared__ float oT[128][16];
  for (int idx = threadIdx.x; idx < 2048; idx += 64) {
    int s = idx & 15, c = idx >> 4;
    int sg = s0 + s;
    oT[c][s] = (sg < n) ? obuf[((size_t)b * CAPM + sg) * ACH + c] : 0.f;
  }
  __syncthreads();
  int co = threadIdx.x;
  float acc[16];
#pragma unroll
  for (int s = 0; s < 16; ++s) acc[s] = 0.f;
  const float* w = wo + (size_t)layer * 128 * 64 + co;
  for (int c = 0; c < 128; ++c) {
    float wv = w[c * 64];
    float hh[16];
#pragma unroll
    for (int sq = 0; sq < 4; ++sq) {
      float4 h4 = *(const float4*)&oT[c][4 * sq];
      hh[4 * sq] = h4.x; hh[4 * sq + 1] = h4.y; hh[4 * sq + 2] = h4.z; hh[4 * sq + 3] = h4.w;
    }
#pragma unroll
    for (int s = 0; s < 16; ++s) acc[s] += hh[s] * wv;
  }
  float bov = bo[layer * 64 + co];
  int smax = min(16, n - s0);
  for (int s = 0; s < smax; ++s)
    feats[((size_t)(b * CAPM) + s0 + s) * 64 + co] += acc[s] + bov;
}

// ---------------- pooled head ------------------------------------------------

__global__ void k_head(const float* __restrict__ feats, const float* __restrict__ wh,
                       const float* __restrict__ bhd, const int* __restrict__ cnt,
                       float* __restrict__ out) {
  int b = blockIdx.x;
  int n = min(cnt[2 * BDIM + b], CAPM);
  int c = threadIdx.x & 63, chunk = threadIdx.x >> 6;   // 256 threads = 4 chunks
  float s = 0.f;
  for (int mm = chunk; mm < n; mm += 4) s += feats[((size_t)(b * CAPM) + mm) * 64 + c];
  __shared__ float red[4][64];
  __shared__ float pooled[64];
  red[chunk][c] = s;
  __syncthreads();
  if (threadIdx.x < 64) {
    float tot = red[0][c] + red[1][c] + red[2][c] + red[3][c];
    pooled[c] = tot / (float)max(n, 1);
  }
  __syncthreads();
  if (threadIdx.x < 4) {
    float o = bhd[threadIdx.x];
#pragma unroll
    for (int c2 = 0; c2 < 64; ++c2) o += pooled[c2] * wh[c2 * 4 + threadIdx.x];
    out[b * 4 + threadIdx.x] = o;
  }
}

// ---------------- launch -----------------------------------------------------

extern "C" void kernel_launch(void* const* d_in, const int* in_sizes, int n_in,
                              void* d_out, int out_size, void* d_ws, size_t ws_size,
                              hipStream_t stream) {
  const float* x   = (const float*)d_in[0];
  const float* w0  = (const float*)d_in[1];
  const float* b0  = (const float*)d_in[2];
  const float* g0  = (const float*)d_in[3];
  const float* be0 = (const float*)d_in[4];
  const float* w1  = (const float*)d_in[5];
  const float* b1  = (const float*)d_in[6];
  const float* g1  = (const float*)d_in[7];
  const float* be1 = (const float*)d_in[8];
  const float* w2  = (const float*)d_in[9];
  const float* b2  = (const float*)d_in[10];
  const float* g2  = (const float*)d_in[11];
  const float* be2 = (const float*)d_in[12];
  const float* wpe = (const float*)d_in[13];
  const float* bpe = (const float*)d_in[14];
  const float* wq  = (const float*)d_in[15];
  const float* bq  = (const float*)d_in[16];
  const float* wk  = (const float*)d_in[17];
  const float* bk  = (const float*)d_in[18];
  const float* wv  = (const float*)d_in[19];
  const float* bv  = (const float*)d_in[20];
  const float* wo  = (const float*)d_in[21];
  const float* bo  = (const float*)d_in[22];
  const float* wh  = (const float*)d_in[23];
  const float* bh  = (const float*)d_in[24];

  int* wsI = (int*)d_ws;
  float* wsF = (float*)d_ws;
  _Float16* qf = (_Float16*)(wsI + E_QF);
  _Float16* kf = (_Float16*)(wsI + E_KF);
  _Float16* vt = (_Float16*)(wsI + E_VT);

  // Zero slot maps + counters. (f16 buffers need no zeroing: padded keys get
  // p == 0.0 exactly, and all resident garbage is finite.)
  hipMemsetAsync(d_ws, 0, E_ZEND * 4, stream);

  // level 0
  k_cnt0<<<dim3(NB0, BDIM), 256, 0, stream>>>(x, wsI + E_BC + 0 * BDIM * 1024);
  k_scan<<<BDIM, 1024, 0, stream>>>(wsI + E_BC + 0 * BDIM * 1024,
                                    wsI + E_BO + 0 * BDIM * 1024,
                                    wsI + E_CNT, NB0, 0);
  k_emit0<<<dim3(NB0, BDIM), 256, 0, stream>>>(x, wsI + E_BO + 0 * BDIM * 1024,
                                               wsI + E_MAP0, wsI + E_LIST0);
  k_y0<<<(BDIM * CAP0 * 32) / 256, 256, 0, stream>>>(
      x, w0, b0, g0, be0, wsI + E_LIST0, wsI + E_CNT, wsF + E_Y0);
  // level 1
  k_cnt1<<<dim3(NB1, BDIM), 256, 0, stream>>>(wsI + E_MAP0, wsI + E_BC + 1 * BDIM * 1024);
  k_scan<<<BDIM, 1024, 0, stream>>>(wsI + E_BC + 1 * BDIM * 1024,
                                    wsI + E_BO + 1 * BDIM * 1024,
                                    wsI + E_CNT, NB1, BDIM);
  k_emit1<<<dim3(NB1, BDIM), 256, 0, stream>>>(wsI + E_MAP0,
                                               wsI + E_BO + 1 * BDIM * 1024,
                                               wsI + E_MAP1, wsI + E_LIST1);
  k_y1<<<BDIM * (CAP1 / 8), 64, 0, stream>>>(
      wsF + E_Y0, w1, b1, g1, be1, wsI + E_MAP0, wsI + E_LIST1, wsI + E_CNT, wsF + E_Y1);
  // level 2
  k_cnt2<<<dim3(NB2, BDIM), 256, 0, stream>>>(wsI + E_MAP1, wsI + E_BC + 2 * BDIM * 1024);
  k_scan<<<BDIM, 1024, 0, stream>>>(wsI + E_BC + 2 * BDIM * 1024,
                                    wsI + E_BO + 2 * BDIM * 1024,
                                    wsI + E_CNT, NB2, 2 * BDIM);
  k_emit2<<<dim3(NB2, BDIM), 256, 0, stream>>>(wsI + E_MAP1,
                                               wsI + E_BO + 2 * BDIM * 1024,
                                               wsI + E_LIST2);
  k_y2<<<BDIM * (CAPM / 8), 64, 0, stream>>>(
      wsF + E_Y1, w2, b2, g2, be2, wsI + E_MAP1, wsI + E_LIST2, wsI + E_CNT, wsF + E_FE);

  for (int layer = 0; layer < 2; ++layer) {
    k_qkv<<<BDIM * (CAPM / 16), 128, 0, stream>>>(
        wsF + E_FE, wsI + E_LIST2, wsI + E_CNT, wpe, bpe, wq, bq, wk, bk, wv, bv,
        layer, qf, kf, vt);
    k_attn<<<BDIM * NHEADS * (CAPM / 16), 64, 0, stream>>>(
        qf, kf, vt, wsI + E_CNT, wsF + E_O);
    k_proj<<<BDIM * (CAPM / 16), 64, 0, stream>>>(
        wsF + E_O, wo, bo, wsI + E_CNT, layer, wsF + E_FE);
  }

  k_head<<<BDIM, 256, 0, stream>>>(wsF + E_FE, wh, bh, wsI + E_CNT, (float*)d_out);
}

// Round 5
// 292.800 us; speedup vs baseline: 5.5072x; 1.3421x over previous
//
#include <hip/hip_runtime.h>

// Problem constants
#define BDIM   8
#define NPIX   250000   // 500*500
#define G1N    62500    // 250*250
#define G2N    15625    // 125*125
#define NB0    977      // ceil(NPIX/256)
#define NB1    245      // ceil(G1N/256)
#define NB2    62       // ceil(G2N/256)
#define CAP0   4096
#define CAP1   4096
#define CAPM   2048
#define CH     64
#define ACH    128
#define NHEADS 4
#define DH     32

static constexpr float BN_INV    = 0.99999500003749969f;   // 1/sqrt(1+1e-5)
static constexpr float ATT_SCALE = 0.17677669529663687f;   // 1/sqrt(32)

typedef _Float16 f16x8 __attribute__((ext_vector_type(8)));
typedef float f32x4 __attribute__((ext_vector_type(4)));

// Workspace word offsets (4-byte units). Zeroed prefix: [0, E_ZEND)
static constexpr size_t E_MAP0  = 0;                                  // int [B*NPIX]
static constexpr size_t E_MAP1  = E_MAP0 + (size_t)BDIM*NPIX;         // int [B*G1N]
static constexpr size_t E_CNT   = E_MAP1 + (size_t)BDIM*G1N;          // int [32]
static constexpr size_t E_ZEND  = E_CNT + 32;
static constexpr size_t E_BC    = E_ZEND;                             // int [3][B][1024]
static constexpr size_t E_BO    = E_BC + (size_t)3*BDIM*1024;         // int [3][B][1024]
static constexpr size_t E_BM    = E_BO + (size_t)3*BDIM*1024;        // ull [3][B][1024][4]
static constexpr size_t E_LIST0 = E_BM + (size_t)3*BDIM*1024*8;      // int [B*CAP0]
static constexpr size_t E_LIST1 = E_LIST0 + (size_t)BDIM*CAP0;
static constexpr size_t E_LIST2 = E_LIST1 + (size_t)BDIM*CAP1;
static constexpr size_t E_Y0    = E_LIST2 + (size_t)BDIM*CAPM;        // f32 [B*CAP0*32]
static constexpr size_t E_Y1    = E_Y0 + (size_t)BDIM*CAP0*32;       // f32 [B*CAP1*64]
static constexpr size_t E_FE    = E_Y1 + (size_t)BDIM*CAP1*64;       // f32 [B*CAPM*64]
static constexpr size_t E_QF    = E_FE + (size_t)BDIM*CAPM*64;       // f16 [32bh][CAPM][32]
static constexpr size_t E_KF    = E_QF + (size_t)32*CAPM*32/2;
static constexpr size_t E_VT    = E_KF + (size_t)32*CAPM*32/2;       // f16 [32bh][32][CAPM]
static constexpr size_t E_PART  = E_VT + (size_t)32*CAPM*32/2;       // f32 [B][16][64]

// ---------------- deterministic compaction: count / scan / emit --------------

__device__ __forceinline__ bool act0(const float* x, int pix, int b) {
  return (pix < NPIX) && (x[(size_t)b * NPIX + pix] != 0.f);
}
__device__ __forceinline__ bool act1(const int* map0, int p, int b) {
  if (p >= G1N) return false;
  int i = p / 250, j = p - i * 250;
  const int* m = map0 + (size_t)b * NPIX + (2 * i) * 500 + 2 * j;
  return (m[0] | m[1] | m[500] | m[501]) != 0;
}
__device__ __forceinline__ bool act2(const int* map1, int p, int b) {
  if (p >= G2N) return false;
  int i = p / 125, j = p - i * 125;
  const int* m = map1 + (size_t)b * G1N + (2 * i) * 250 + 2 * j;
  return (m[0] | m[1] | m[250] | m[251]) != 0;
}

#define COUNT_BODY(ACT_EXPR)                                            \
  int idx = blockIdx.x * 256 + threadIdx.x;                             \
  int b = blockIdx.y;                                                   \
  bool act = (ACT_EXPR);                                                \
  unsigned long long mask = __ballot(act);                              \
  __shared__ int wc[4];                                                 \
  if ((threadIdx.x & 63) == 0) {                                        \
    wc[threadIdx.x >> 6] = __popcll(mask);                              \
    bm[((size_t)b * 1024 + blockIdx.x) * 4 + (threadIdx.x >> 6)] = mask;\
  }                                                                     \
  __syncthreads();                                                      \
  if (threadIdx.x == 0)                                                 \
    bcnt[b * 1024 + blockIdx.x] = wc[0] + wc[1] + wc[2] + wc[3];

__global__ void k_cnt0(const float* __restrict__ x, int* __restrict__ bcnt,
                       unsigned long long* __restrict__ bm) {
  COUNT_BODY(act0(x, idx, b))
}
__global__ void k_cnt1(const int* __restrict__ map0, int* __restrict__ bcnt,
                       unsigned long long* __restrict__ bm) {
  COUNT_BODY(act1(map0, idx, b))
}
__global__ void k_cnt2(const int* __restrict__ map1, int* __restrict__ bcnt,
                       unsigned long long* __restrict__ bm) {
  COUNT_BODY(act2(map1, idx, b))
}

// one block/image, 256 threads, shfl scan (1 barrier). nblk <= 1024.
__global__ __launch_bounds__(256) void k_scan(const int* __restrict__ bcnt,
                                              int* __restrict__ boff,
                                              int* __restrict__ cnt,
                                              int nblk, int cbase) {
  int b = blockIdx.x;
  int t = threadIdx.x;
  int base = t * 4;
  int v[4];
  int ts = 0;
#pragma unroll
  for (int u = 0; u < 4; ++u) {
    v[u] = (base + u < nblk) ? bcnt[b * 1024 + base + u] : 0;
    ts += v[u];
  }
  int lane = t & 63, w = t >> 6;
  int incl = ts;
#pragma unroll
  for (int off = 1; off < 64; off <<= 1) {
    int o = __shfl_up(incl, off, 64);
    if (lane >= off) incl += o;
  }
  __shared__ int wsum[4];
  if (lane == 63) wsum[w] = incl;
  __syncthreads();
  int woff = 0;
#pragma unroll
  for (int k = 0; k < 3; ++k) if (k < w) woff += wsum[k];
  int run = woff + incl - ts;
#pragma unroll
  for (int u = 0; u < 4; ++u) {
    if (base + u < nblk) boff[b * 1024 + base + u] = run;
    run += v[u];
  }
  if (t == 255) cnt[cbase + b] = run;
}

// emit: replay stored ballot masks (no recompute / no re-read of inputs)
#define EMIT_PROLOG                                                     \
  int idx = blockIdx.x * 256 + threadIdx.x;                             \
  int b = blockIdx.y;                                                   \
  int lane = threadIdx.x & 63;                                          \
  unsigned long long mask =                                             \
      bm[((size_t)b * 1024 + blockIdx.x) * 4 + (threadIdx.x >> 6)];     \
  bool act = (mask >> lane) & 1;                                        \
  __shared__ int wbase[4];                                              \
  if (lane == 0) wbase[threadIdx.x >> 6] = __popcll(mask);              \
  __syncthreads();                                                      \
  if (threadIdx.x == 0) {                                               \
    int s = boff[b * 1024 + blockIdx.x];                                \
    for (int w = 0; w < 4; ++w) { int c = wbase[w]; wbase[w] = s; s += c; } \
  }                                                                     \
  __syncthreads();                                                      \
  int slot = wbase[threadIdx.x >> 6] + __popcll(mask & ((1ull << lane) - 1ull));

__global__ void k_emit0(const unsigned long long* __restrict__ bm,
                        const int* __restrict__ boff,
                        int* __restrict__ map0, int* __restrict__ list0) {
  EMIT_PROLOG
  if (act && slot < CAP0) {
    list0[b * CAP0 + slot] = idx;
    map0[(size_t)b * NPIX + idx] = slot + 1;
  }
}
__global__ void k_emit1(const unsigned long long* __restrict__ bm,
                        const int* __restrict__ boff,
                        int* __restrict__ map1, int* __restrict__ list1) {
  EMIT_PROLOG
  if (act && slot < CAP1) {
    list1[b * CAP1 + slot] = idx;
    map1[(size_t)b * G1N + idx] = slot + 1;
  }
}
__global__ void k_emit2(const unsigned long long* __restrict__ bm,
                        const int* __restrict__ boff,
                        int* __restrict__ list2) {
  EMIT_PROLOG
  if (act && slot < CAPM) list2[b * CAPM + slot] = idx;
}

// ---------------- sparse convs -----------------------------------------------

__global__ void k_y0(const float* __restrict__ x, const float* __restrict__ w0,
                     const float* __restrict__ b0, const float* __restrict__ g0,
                     const float* __restrict__ be0,
                     const int* __restrict__ list0, const int* __restrict__ cnt,
                     float* __restrict__ y0) {
  int t = blockIdx.x * 256 + threadIdx.x;
  int b = t >> 17;
  int r = t & 131071;
  int slot = r >> 5, c = r & 31;
  int n = min(cnt[b], CAP0);
  if (slot >= n) return;
  int pix = list0[b * CAP0 + slot];
  int i = pix / 500, j = pix - i * 500;
  float acc = b0[c];
#pragma unroll
  for (int di = 0; di < 3; ++di) {
    int ii = i + di - 1;
    if ((unsigned)ii >= 500u) continue;
#pragma unroll
    for (int dj = 0; dj < 3; ++dj) {
      int jj = j + dj - 1;
      if ((unsigned)jj >= 500u) continue;
      acc += x[(size_t)b * NPIX + ii * 500 + jj] * w0[(di * 3 + dj) * 32 + c];
    }
  }
  float o = g0[c] * acc * BN_INV + be0[c];
  y0[((size_t)(b * CAP0) + slot) * 32 + c] = fmaxf(o, 0.f);
}

__global__ void k_y1(const float* __restrict__ y0, const float* __restrict__ w1,
                     const float* __restrict__ b1, const float* __restrict__ g1,
                     const float* __restrict__ be1,
                     const int* __restrict__ map0, const int* __restrict__ list1,
                     const int* __restrict__ cnt, float* __restrict__ y1) {
  int b = blockIdx.x >> 9;          // CAP1/8 = 512
  int sblk = blockIdx.x & 511;
  int s0 = sblk * 8;
  int n = min(cnt[BDIM + b], CAP1);
  if (s0 >= n) return;
  __shared__ float inT[4][32][8];
  for (int idx = threadIdx.x; idx < 1024; idx += 64) {
    int s = idx & 7;
    int r = idx >> 3;
    int ci = r & 31, pp = r >> 5;
    float v = 0.f;
    int sg = s0 + s;
    if (sg < n) {
      int p = list1[b * CAP1 + sg];
      int i = p / 250, j = p - i * 250;
      int sm = map0[(size_t)b * NPIX + (2 * i + (pp >> 1)) * 500 + (2 * j + (pp & 1))];
      if (sm) v = y0[((size_t)(b * CAP0) + (sm - 1)) * 32 + ci];
    }
    inT[pp][ci][s] = v;
  }
  __syncthreads();
  int co = threadIdx.x;
  float acc[8];
#pragma unroll
  for (int s = 0; s < 8; ++s) acc[s] = b1[co];
#pragma unroll 2
  for (int pp = 0; pp < 4; ++pp)
    for (int ci = 0; ci < 32; ++ci) {
      float wv = w1[((pp << 5) + ci) * 64 + co];
      float4 i0 = *(const float4*)&inT[pp][ci][0];
      float4 i1 = *(const float4*)&inT[pp][ci][4];
      acc[0] += i0.x * wv; acc[1] += i0.y * wv; acc[2] += i0.z * wv; acc[3] += i0.w * wv;
      acc[4] += i1.x * wv; acc[5] += i1.y * wv; acc[6] += i1.z * wv; acc[7] += i1.w * wv;
    }
  int smax = min(8, n - s0);
  for (int s = 0; s < smax; ++s) {
    float o = g1[co] * acc[s] * BN_INV + be1[co];
    y1[((size_t)(b * CAP1) + s0 + s) * 64 + co] = fmaxf(o, 0.f);
  }
}

__global__ void k_y2(const float* __restrict__ y1, const float* __restrict__ w2,
                     const float* __restrict__ b2, const float* __restrict__ g2,
                     const float* __restrict__ be2,
                     const int* __restrict__ map1, const int* __restrict__ list2,
                     const int* __restrict__ cnt, float* __restrict__ feats) {
  int b = blockIdx.x >> 8;          // CAPM/8 = 256
  int sblk = blockIdx.x & 255;
  int s0 = sblk * 8;
  int n = min(cnt[2 * BDIM + b], CAPM);
  if (s0 >= n) return;
  __shared__ float inT[4][64][8];
  for (int idx = threadIdx.x; idx < 2048; idx += 64) {
    int s = idx & 7;
    int r = idx >> 3;
    int ci = r & 63, pp = r >> 6;
    float v = 0.f;
    int sg = s0 + s;
    if (sg < n) {
      int p = list2[b * CAPM + sg];
      int i = p / 125, j = p - i * 125;
      int sm = map1[(size_t)b * G1N + (2 * i + (pp >> 1)) * 250 + (2 * j + (pp & 1))];
      if (sm) v = y1[((size_t)(b * CAP1) + (sm - 1)) * 64 + ci];
    }
    inT[pp][ci][s] = v;
  }
  __syncthreads();
  int co = threadIdx.x;
  float acc[8];
#pragma unroll
  for (int s = 0; s < 8; ++s) acc[s] = b2[co];
#pragma unroll 2
  for (int pp = 0; pp < 4; ++pp)
    for (int ci = 0; ci < 64; ++ci) {
      float wv = w2[((pp << 6) + ci) * 64 + co];
      float4 i0 = *(const float4*)&inT[pp][ci][0];
      float4 i1 = *(const float4*)&inT[pp][ci][4];
      acc[0] += i0.x * wv; acc[1] += i0.y * wv; acc[2] += i0.z * wv; acc[3] += i0.w * wv;
      acc[4] += i1.x * wv; acc[5] += i1.y * wv; acc[6] += i1.z * wv; acc[7] += i1.w * wv;
    }
  int smax = min(8, n - s0);
  for (int s = 0; s < smax; ++s) {
    float o = g2[co] * acc[s] * BN_INV + be2[co];
    feats[((size_t)(b * CAPM) + s0 + s) * 64 + co] = fmaxf(o, 0.f);
  }
}

// ---------------- QKV projection -> f16 buffers ------------------------------

__global__ void k_qkv(const float* __restrict__ feats, const int* __restrict__ list2,
                      const int* __restrict__ cnt,
                      const float* __restrict__ wpe, const float* __restrict__ bpe,
                      const float* __restrict__ wq, const float* __restrict__ bq,
                      const float* __restrict__ wk, const float* __restrict__ bk,
                      const float* __restrict__ wv, const float* __restrict__ bv,
                      int layer, _Float16* __restrict__ qf, _Float16* __restrict__ kf,
                      _Float16* __restrict__ vt) {
  int b = blockIdx.x >> 7;          // CAPM/16 = 128
  int sblk = blockIdx.x & 127;
  int s0 = sblk * 16;
  int n = min(cnt[2 * BDIM + b], CAPM);
  if (s0 >= n) return;
  __shared__ float hT[64][16];
  for (int idx = threadIdx.x; idx < 1024; idx += 128) {
    int s = idx & 15, c = idx >> 4;
    float hv = 0.f;
    int sg = s0 + s;
    if (sg < n) {
      int p = list2[b * CAPM + sg];
      int i = p / 125, j = p - i * 125;
      hv = feats[((size_t)(b * CAPM) + sg) * 64 + c]
         + (float)i * (1.f / 125.f) * wpe[(layer * 2 + 0) * 64 + c]
         + (float)j * (1.f / 125.f) * wpe[(layer * 2 + 1) * 64 + c]
         + bpe[layer * 64 + c];
    }
    hT[c][s] = hv;
  }
  __syncthreads();
  int o = threadIdx.x;
  float accq[16], acck[16], accv[16];
  float bqv = bq[layer * 128 + o], bkv = bk[layer * 128 + o], bvv = bv[layer * 128 + o];
#pragma unroll
  for (int s = 0; s < 16; ++s) { accq[s] = bqv; acck[s] = bkv; accv[s] = bvv; }
  const float* wq_ = wq + (size_t)layer * 64 * 128 + o;
  const float* wk_ = wk + (size_t)layer * 64 * 128 + o;
  const float* wv_ = wv + (size_t)layer * 64 * 128 + o;
  for (int c = 0; c < 64; ++c) {
    float wqv = wq_[c * 128], wkv = wk_[c * 128], wvv = wv_[c * 128];
    float hh[16];
#pragma unroll
    for (int sq = 0; sq < 4; ++sq) {
      float4 h4 = *(const float4*)&hT[c][4 * sq];
      hh[4 * sq] = h4.x; hh[4 * sq + 1] = h4.y; hh[4 * sq + 2] = h4.z; hh[4 * sq + 3] = h4.w;
    }
#pragma unroll
    for (int s = 0; s < 16; ++s) {
      accq[s] += hh[s] * wqv; acck[s] += hh[s] * wkv; accv[s] += hh[s] * wvv;
    }
  }
  int hd = o >> 5, d = o & 31;
  size_t bh = (size_t)(b * NHEADS + hd);
  int smax = min(16, n - s0);
  for (int s = 0; s < smax; ++s) {
    size_t rb = (bh * CAPM + s0 + s) * 32 + d;
    qf[rb] = (_Float16)accq[s];
    kf[rb] = (_Float16)acck[s];
    vt[(bh * 32 + d) * CAPM + s0 + s] = (_Float16)accv[s];
  }
}

// ---------------- MFMA flash attention + fused out-proj ----------------------
// Block = (b, 16-query tile), 4 waves = 4 heads. Per-wave private P (XOR-
// swizzled). S^T = K·Q^T; softmax per column qr; per-tile rescale f and final
// l transposed through LDS to PV rows. After the flash loop, normalized per-
// head outputs exchange via oT[128][17] and the block applies the 128->64
// output projection + bias + residual directly into feats.

union U4H8 { uint4 u; f16x8 h; };
union PKU  { _Float16 h[2]; unsigned int u; };

__global__ __launch_bounds__(256) void k_attn(
    const _Float16* __restrict__ qf, const _Float16* __restrict__ kf,
    const _Float16* __restrict__ vt, const int* __restrict__ cnt,
    const float* __restrict__ wo, const float* __restrict__ bo, int layer,
    float* __restrict__ feats) {
  int qt = blockIdx.x & 127;          // CAPM/16
  int b  = blockIdx.x >> 7;
  int n = min(cnt[2 * BDIM + b], CAPM);
  int q0 = qt * 16;
  if (q0 >= n) return;               // uniform across block
  int h = threadIdx.x >> 6;
  int lane = threadIdx.x & 63;
  int g = lane >> 4, qr = lane & 15;
  size_t bh = (size_t)(b * NHEADS + h) * CAPM;
  const _Float16* vbase = vt + (size_t)(b * NHEADS + h) * 32 * CAPM;
  f16x8 fq = *(const f16x8*)(qf + (bh + q0 + qr) * 32 + g * 8);   // Q B-frag
  f32x4 acc0 = {0.f, 0.f, 0.f, 0.f}, acc1 = {0.f, 0.f, 0.f, 0.f};
  float m = -1e30f, l = 0.f;
  __shared__ unsigned int P4[4][512];  // per-wave 16q x 64k f16, swizzled
  __shared__ float Lf4[4][16];
  __shared__ float Ll4[4][16];
  __shared__ float oT[128][17];        // [attn ch][site], padded
  unsigned int* P = P4[h];
  float* Lf = Lf4[h];
  int swz = (qr & 7) << 2;

  for (int t0 = 0; t0 < n; t0 += 64) {
    f32x4 st[4];
#pragma unroll
    for (int t = 0; t < 4; ++t) {
      f16x8 ka = *(const f16x8*)(kf + (bh + t0 + 16 * t + qr) * 32 + g * 8);
      f32x4 z = {0.f, 0.f, 0.f, 0.f};
      st[t] = __builtin_amdgcn_mfma_f32_16x16x32_f16(ka, fq, z, 0, 0, 0);
    }
    if (t0 + 64 > n) {                 // tail: mask keys >= n
#pragma unroll
      for (int t = 0; t < 4; ++t)
#pragma unroll
        for (int r = 0; r < 4; ++r)
          if (t0 + 16 * t + 4 * g + r >= n) st[t][r] = -1e30f;
    }
    float tm = -1e30f;
#pragma unroll
    for (int t = 0; t < 4; ++t)
#pragma unroll
      for (int r = 0; r < 4; ++r) tm = fmaxf(tm, st[t][r]);
    tm = fmaxf(tm, __shfl_xor(tm, 16));
    tm = fmaxf(tm, __shfl_xor(tm, 32));
    float mn = fmaxf(m, tm * ATT_SCALE);
    float f = __expf(m - mn);          // rescale factor for query qr
    m = mn;
    if (g == 0) Lf[qr] = f;
    float ls = 0.f;
#pragma unroll
    for (int t = 0; t < 4; ++t) {
      PKU a, c;
      float p0 = __expf(st[t][0] * ATT_SCALE - mn);
      float p1 = __expf(st[t][1] * ATT_SCALE - mn);
      float p2 = __expf(st[t][2] * ATT_SCALE - mn);
      float p3 = __expf(st[t][3] * ATT_SCALE - mn);
      a.h[0] = (_Float16)p0; a.h[1] = (_Float16)p1;
      c.h[0] = (_Float16)p2; c.h[1] = (_Float16)p3;
      ls += (float)a.h[0] + (float)a.h[1] + (float)c.h[0] + (float)c.h[1];
      int w = qr * 32 + 8 * t + 2 * g;
      P[w ^ swz] = a.u;
      P[(w + 1) ^ swz] = c.u;
    }
    ls += __shfl_xor(ls, 16);
    ls += __shfl_xor(ls, 32);
    l = l * f + ls;
    __syncthreads();                   // P + Lf visible (all waves same trip)
    U4H8 pa0, pa1;                     // A-frags: row=query qr, keys 8g.. (+32)
    pa0.u = *(const uint4*)&P[(qr * 32 + 4 * g) ^ swz];
    pa1.u = *(const uint4*)&P[(qr * 32 + 16 + 4 * g) ^ swz];
    float fr0 = Lf[4 * g + 0], fr1 = Lf[4 * g + 1];
    float fr2 = Lf[4 * g + 2], fr3 = Lf[4 * g + 3];
    acc0[0] *= fr0; acc0[1] *= fr1; acc0[2] *= fr2; acc0[3] *= fr3;
    acc1[0] *= fr0; acc1[1] *= fr1; acc1[2] *= fr2; acc1[3] *= fr3;
    __syncthreads();                   // protect P/Lf for next iter
    f16x8 v00 = *(const f16x8*)(vbase + (size_t)qr * CAPM + t0 + g * 8);
    f16x8 v01 = *(const f16x8*)(vbase + (size_t)(16 + qr) * CAPM + t0 + g * 8);
    f16x8 v10 = *(const f16x8*)(vbase + (size_t)qr * CAPM + t0 + 32 + g * 8);
    f16x8 v11 = *(const f16x8*)(vbase + (size_t)(16 + qr) * CAPM + t0 + 32 + g * 8);
    acc0 = __builtin_amdgcn_mfma_f32_16x16x32_f16(pa0.h, v00, acc0, 0, 0, 0);
    acc1 = __builtin_amdgcn_mfma_f32_16x16x32_f16(pa0.h, v01, acc1, 0, 0, 0);
    acc0 = __builtin_amdgcn_mfma_f32_16x16x32_f16(pa1.h, v10, acc0, 0, 0, 0);
    acc1 = __builtin_amdgcn_mfma_f32_16x16x32_f16(pa1.h, v11, acc1, 0, 0, 0);
  }
  if (g == 0) Ll4[h][qr] = l;
  __syncthreads();
#pragma unroll
  for (int r = 0; r < 4; ++r) {
    float inv = 1.f / Ll4[h][4 * g + r];
    oT[h * 32 + qr][4 * g + r] = acc0[r] * inv;
    oT[h * 32 + 16 + qr][4 * g + r] = acc1[r] * inv;
  }
  __syncthreads();
  // fused 128->64 projection + bias + residual: wave h -> sites 4h..4h+3
  int co = lane;
  float pacc[4] = {0.f, 0.f, 0.f, 0.f};
  const float* w = wo + (size_t)layer * 128 * 64 + co;
  for (int c = 0; c < 128; ++c) {
    float wv = w[c * 64];
#pragma unroll
    for (int u = 0; u < 4; ++u) pacc[u] += oT[c][4 * h + u] * wv;
  }
  float bov = bo[layer * 64 + co];
#pragma unroll
  for (int u = 0; u < 4; ++u) {
    int tok = q0 + 4 * h + u;
    if (tok < n) feats[((size_t)(b * CAPM) + tok) * 64 + co] += pacc[u] + bov;
  }
}

// ---------------- pooled head: 2-stage deterministic reduce ------------------

__global__ void k_head1(const float* __restrict__ feats, const int* __restrict__ cnt,
                        float* __restrict__ part) {
  int b = blockIdx.x >> 4;
  int chunk = blockIdx.x & 15;
  int n = min(cnt[2 * BDIM + b], CAPM);
  int c = threadIdx.x & 63, sub = threadIdx.x >> 6;
  int lo = chunk * 128, hi = min(n, lo + 128);
  float s = 0.f;
  for (int mm = lo + sub; mm < hi; mm += 4)
    s += feats[((size_t)(b * CAPM) + mm) * 64 + c];
  __shared__ float red[4][64];
  red[sub][c] = s;
  __syncthreads();
  if (threadIdx.x < 64)
    part[(b * 16 + chunk) * 64 + c] = red[0][c] + red[1][c] + red[2][c] + red[3][c];
}

__global__ void k_head2(const float* __restrict__ part, const float* __restrict__ wh,
                        const float* __restrict__ bhd, const int* __restrict__ cnt,
                        float* __restrict__ out) {
  int b = blockIdx.x;
  int n = min(cnt[2 * BDIM + b], CAPM);
  int c = threadIdx.x;
  float s = 0.f;
#pragma unroll
  for (int k = 0; k < 16; ++k) s += part[(b * 16 + k) * 64 + c];
  __shared__ float pooled[64];
  pooled[c] = s / (float)max(n, 1);
  __syncthreads();
  if (c < 4) {
    float o = bhd[c];
#pragma unroll
    for (int c2 = 0; c2 < 64; ++c2) o += pooled[c2] * wh[c2 * 4 + c];
    out[b * 4 + c] = o;
  }
}

// ---------------- launch -----------------------------------------------------

extern "C" void kernel_launch(void* const* d_in, const int* in_sizes, int n_in,
                              void* d_out, int out_size, void* d_ws, size_t ws_size,
                              hipStream_t stream) {
  const float* x   = (const float*)d_in[0];
  const float* w0  = (const float*)d_in[1];
  const float* b0  = (const float*)d_in[2];
  const float* g0  = (const float*)d_in[3];
  const float* be0 = (const float*)d_in[4];
  const float* w1  = (const float*)d_in[5];
  const float* b1  = (const float*)d_in[6];
  const float* g1  = (const float*)d_in[7];
  const float* be1 = (const float*)d_in[8];
  const float* w2  = (const float*)d_in[9];
  const float* b2  = (const float*)d_in[10];
  const float* g2  = (const float*)d_in[11];
  const float* be2 = (const float*)d_in[12];
  const float* wpe = (const float*)d_in[13];
  const float* bpe = (const float*)d_in[14];
  const float* wq  = (const float*)d_in[15];
  const float* bq  = (const float*)d_in[16];
  const float* wk  = (const float*)d_in[17];
  const float* bk  = (const float*)d_in[18];
  const float* wv  = (const float*)d_in[19];
  const float* bv  = (const float*)d_in[20];
  const float* wo  = (const float*)d_in[21];
  const float* bo  = (const float*)d_in[22];
  const float* wh  = (const float*)d_in[23];
  const float* bh  = (const float*)d_in[24];

  int* wsI = (int*)d_ws;
  float* wsF = (float*)d_ws;
  unsigned long long* bm = (unsigned long long*)(wsI + E_BM);
  _Float16* qf = (_Float16*)(wsI + E_QF);
  _Float16* kf = (_Float16*)(wsI + E_KF);
  _Float16* vt = (_Float16*)(wsI + E_VT);

  // Zero slot maps + counters only.
  hipMemsetAsync(d_ws, 0, E_ZEND * 4, stream);

  // level 0
  k_cnt0<<<dim3(NB0, BDIM), 256, 0, stream>>>(x, wsI + E_BC + 0 * BDIM * 1024,
                                              bm + 0 * BDIM * 4096);
  k_scan<<<BDIM, 256, 0, stream>>>(wsI + E_BC + 0 * BDIM * 1024,
                                   wsI + E_BO + 0 * BDIM * 1024,
                                   wsI + E_CNT, NB0, 0);
  k_emit0<<<dim3(NB0, BDIM), 256, 0, stream>>>(bm + 0 * BDIM * 4096,
                                               wsI + E_BO + 0 * BDIM * 1024,
                                               wsI + E_MAP0, wsI + E_LIST0);
  k_y0<<<(BDIM * CAP0 * 32) / 256, 256, 0, stream>>>(
      x, w0, b0, g0, be0, wsI + E_LIST0, wsI + E_CNT, wsF + E_Y0);
  // level 1
  k_cnt1<<<dim3(NB1, BDIM), 256, 0, stream>>>(wsI + E_MAP0,
                                              wsI + E_BC + 1 * BDIM * 1024,
                                              bm + 1 * BDIM * 4096);
  k_scan<<<BDIM, 256, 0, stream>>>(wsI + E_BC + 1 * BDIM * 1024,
                                   wsI + E_BO + 1 * BDIM * 1024,
                                   wsI + E_CNT, NB1, BDIM);
  k_emit1<<<dim3(NB1, BDIM), 256, 0, stream>>>(bm + 1 * BDIM * 4096,
                                               wsI + E_BO + 1 * BDIM * 1024,
                                               wsI + E_MAP1, wsI + E_LIST1);
  k_y1<<<BDIM * (CAP1 / 8), 64, 0, stream>>>(
      wsF + E_Y0, w1, b1, g1, be1, wsI + E_MAP0, wsI + E_LIST1, wsI + E_CNT, wsF + E_Y1);
  // level 2
  k_cnt2<<<dim3(NB2, BDIM), 256, 0, stream>>>(wsI + E_MAP1,
                                              wsI + E_BC + 2 * BDIM * 1024,
                                              bm + 2 * BDIM * 4096);
  k_scan<<<BDIM, 256, 0, stream>>>(wsI + E_BC + 2 * BDIM * 1024,
                                   wsI + E_BO + 2 * BDIM * 1024,
                                   wsI + E_CNT, NB2, 2 * BDIM);
  k_emit2<<<dim3(NB2, BDIM), 256, 0, stream>>>(bm + 2 * BDIM * 4096,
                                               wsI + E_BO + 2 * BDIM * 1024,
                                               wsI + E_LIST2);
  k_y2<<<BDIM * (CAPM / 8), 64, 0, stream>>>(
      wsF + E_Y1, w2, b2, g2, be2, wsI + E_MAP1, wsI + E_LIST2, wsI + E_CNT, wsF + E_FE);

  for (int layer = 0; layer < 2; ++layer) {
    k_qkv<<<BDIM * (CAPM / 16), 128, 0, stream>>>(
        wsF + E_FE, wsI + E_LIST2, wsI + E_CNT, wpe, bpe, wq, bq, wk, bk, wv, bv,
        layer, qf, kf, vt);
    k_attn<<<BDIM * (CAPM / 16), 256, 0, stream>>>(
        qf, kf, vt, wsI + E_CNT, wo, bo, layer, wsF + E_FE);
  }

  k_head1<<<BDIM * 16, 256, 0, stream>>>(wsF + E_FE, wsI + E_CNT, wsF + E_PART);
  k_head2<<<BDIM, 64, 0, stream>>>(wsF + E_PART, wh, bh, wsI + E_CNT, (float*)d_out);
}